// Round 2
// baseline (5168.768 us; speedup 1.0000x reference)
//
#include <hip/hip_runtime.h>
#include <hip/hip_bf16.h>

#define NV 40000
#define FD 256
#define HD 128
#define ED 640000
#define NG 3
#define NH (NV*HD)

#define CH  64            // chunks per graph
#define EPC (ED/CH)       // 10000 edges per chunk
#define NB  625           // buckets of 64 nodes: 625*64 = 40000 exactly
#define TOT (NB*CH)       // 40000 hist cells per graph
#define OFFS (TOT+2)

typedef unsigned short u16;
typedef unsigned int   u32;
typedef __attribute__((ext_vector_type(8))) u16    u16x8;
typedef __attribute__((ext_vector_type(8))) __bf16 bf16x8;
typedef __attribute__((ext_vector_type(4))) float  f32x4;

__device__ inline u16 f2b(float f){ __bf16 h = (__bf16)f; return __builtin_bit_cast(u16, h); }
__device__ inline float b2f(u16 u){ u32 x = ((u32)u)<<16; return __builtin_bit_cast(float, x); }

// ---------------- binning: hist -> scan -> scatter -> deg ----------------
__global__ __launch_bounds__(256) void hist_k(const int* __restrict__ ei, int* __restrict__ hist){
  int ch = blockIdx.x, g = blockIdx.y, t = threadIdx.x;
  __shared__ int h[NB];
  for (int i=t;i<NB;i+=256) h[i]=0;
  __syncthreads();
  const int* cc = ei + (long)g*2*ED + ED + ch*EPC;
  for (int j=t;j<EPC;j+=256) atomicAdd(&h[cc[j]>>6],1);
  __syncthreads();
  int* hg = hist + (long)g*TOT;
  for (int b=t;b<NB;b+=256) hg[b*CH+ch]=h[b];
}

__global__ void scan2_k(const int* __restrict__ hist, int* __restrict__ off){
  int g = blockIdx.x;
  const int* src = hist + (long)g*TOT;
  int* dst = off + (long)g*OFFS;
  __shared__ int wsum[16];
  __shared__ int carrySh;
  int tid=threadIdx.x, lane=tid&63, wv=tid>>6;
  if (tid==0) carrySh=0;
  __syncthreads();
  for (int base=0;base<TOT;base+=1024){
    int i=base+tid;
    int v=(i<TOT)?src[i]:0;
    int s=v;
    #pragma unroll
    for (int d=1;d<64;d<<=1){ int t2=__shfl_up(s,d,64); if(lane>=d) s+=t2; }
    if(lane==63) wsum[wv]=s;
    __syncthreads();
    int carry=carrySh;
    if(wv==0){
      int t3=(lane<16)?wsum[lane]:0;
      #pragma unroll
      for(int d=1;d<16;d<<=1){ int u=__shfl_up(t3,d,64); if(lane>=d) t3+=u; }
      if(lane<16) wsum[lane]=t3;
    }
    __syncthreads();
    int woff=(wv>0)?wsum[wv-1]:0;
    int incl=s+woff+carry;
    if(i<TOT){ dst[i]=incl-v; if(i==TOT-1) dst[TOT]=incl; }
    __syncthreads();
    if(tid==1023) carrySh=incl;
    __syncthreads();
  }
}

__global__ __launch_bounds__(256) void scat_k(const int* __restrict__ ei, const int* __restrict__ off,
                                              u32* __restrict__ temp){
  int ch=blockIdx.x, g=blockIdx.y, t=threadIdx.x;
  __shared__ int cur[NB];
  const int* offg = off + (long)g*OFFS;
  for (int b=t;b<NB;b+=256) cur[b]=offg[b*CH+ch];
  __syncthreads();
  const int* rr = ei + (long)g*2*ED + ch*EPC;
  const int* cc = rr + ED;
  u32* tg = temp + (long)g*ED;
  for (int j=t;j<EPC;j+=256){
    int r=rr[j], c=cc[j];
    int pos=atomicAdd(&cur[c>>6],1);
    tg[pos]=((u32)(c&63)<<16)|(u32)r;
  }
}

__global__ __launch_bounds__(64) void deg_k(const u32* __restrict__ temp, const int* __restrict__ off,
                                            float* __restrict__ dinv){
  int b=blockIdx.x, g=blockIdx.y, lane=threadIdx.x;
  __shared__ int cnt[64];
  cnt[lane]=0;
  __syncthreads();
  const int* offg = off + (long)g*OFFS;
  int s=offg[b*CH], e=offg[(b+1)*CH];
  const u32* tg = temp + (long)g*ED;
  for (int i=s+lane;i<e;i+=64) atomicAdd(&cnt[tg[i]>>16],1);
  __syncthreads();
  dinv[(long)g*NV + b*64 + lane] = rsqrtf((float)cnt[lane]+1.0f);
}

// --------------- weight transpose: [K][N] f32 -> [N][K] bf16, batched ----------
__global__ void tr_k(const float* __restrict__ src, u16* __restrict__ dst,
                     int K, int NN, long total){
  long idx = (long)blockIdx.x*256 + threadIdx.x;
  if (idx >= total) return;
  long per = (long)K*NN;
  long mat = idx / per; long rem = idx - mat*per;
  int k = (int)(rem / NN), c = (int)(rem - (long)k*NN);
  dst[mat*per + (long)c*K + k] = f2b(src[idx]);
}

// --------------- bf16 MFMA GEMM: C = A @ Bt^T (+bias). 128x128 tile, BK=64 ------
template<int AF32>
__global__ __launch_bounds__(256) void gemm_k(
    const void* __restrict__ A_, long sA,
    const u16* __restrict__ Bt, long sB,
    const float* __restrict__ bias, long sBias,
    float* __restrict__ Cf, long sCf,
    u16* __restrict__ Cb, long sCb,
    int M, int N, int K)
{
  __shared__ __align__(16) u16 lsA[128*64];
  __shared__ __align__(16) u16 lsB[128*64];
  const int gz = blockIdx.z;
  const float* Af = nullptr; const u16* Ab = nullptr;
  if (AF32) Af = (const float*)A_ + (long)gz*sA;
  else      Ab = (const u16*) A_ + (long)gz*sA;
  const u16* Bp = Bt + (long)gz*sB;
  const int t = threadIdx.x;
  const int lane = t & 63, wv = t >> 6, wm = wv >> 1, wn = wv & 1;
  const int lr = lane & 15, lq = lane >> 4;
  const int ar = t >> 1, ah = t & 1;
  const long grow = (long)blockIdx.x*128 + ar;
  const int colB = blockIdx.y*128 + ar;

  f32x4 acc[4][4];
  #pragma unroll
  for (int m=0;m<4;m++)
    #pragma unroll
    for (int n=0;n<4;n++) acc[m][n] = (f32x4)(0.0f);

  for (int k0=0; k0<K; k0+=64){
    if (k0) __syncthreads();
    u16x8 av[4];
    if (grow < M){
      if (AF32){
        const float4* s = (const float4*)(Af + grow*(long)K + k0 + ah*32);
        #pragma unroll
        for (int i=0;i<4;i++){
          float4 v0 = s[i*2], v1 = s[i*2+1];
          u16x8 w;
          w[0]=f2b(v0.x); w[1]=f2b(v0.y); w[2]=f2b(v0.z); w[3]=f2b(v0.w);
          w[4]=f2b(v1.x); w[5]=f2b(v1.y); w[6]=f2b(v1.z); w[7]=f2b(v1.w);
          av[i] = w;
        }
      } else {
        const u16x8* s = (const u16x8*)(Ab + grow*(long)K + k0 + ah*32);
        #pragma unroll
        for (int i=0;i<4;i++) av[i] = s[i];
      }
    } else {
      #pragma unroll
      for (int i=0;i<4;i++) av[i] = (u16x8)((u16)0);
    }
    #pragma unroll
    for (int i=0;i<4;i++){
      int q = ah*4 + i;
      *(u16x8*)&lsA[ar*64 + ((q ^ (ar&7))<<3)] = av[i];
    }
    {
      const u16x8* s = (const u16x8*)(Bp + (long)colB*K + k0 + ah*32);
      #pragma unroll
      for (int i=0;i<4;i++){
        int q = ah*4 + i;
        *(u16x8*)&lsB[ar*64 + ((q ^ (ar&7))<<3)] = s[i];
      }
    }
    __syncthreads();
    #pragma unroll
    for (int kk=0; kk<2; kk++){
      bf16x8 afr[4], bfr[4];
      #pragma unroll
      for (int m=0;m<4;m++){
        int r = wm*64 + m*16 + lr;
        int q = kk*4 + lq;
        afr[m] = __builtin_bit_cast(bf16x8, *(const u16x8*)&lsA[r*64 + ((q ^ (r&7))<<3)]);
      }
      #pragma unroll
      for (int n=0;n<4;n++){
        int r = wn*64 + n*16 + lr;
        int q = kk*4 + lq;
        bfr[n] = __builtin_bit_cast(bf16x8, *(const u16x8*)&lsB[r*64 + ((q ^ (r&7))<<3)]);
      }
      #pragma unroll
      for (int m=0;m<4;m++)
        #pragma unroll
        for (int n=0;n<4;n++)
          acc[m][n] = __builtin_amdgcn_mfma_f32_16x16x32_bf16(afr[m], bfr[n], acc[m][n], 0, 0, 0);
    }
  }
  #pragma unroll
  for (int m=0;m<4;m++){
    long gr0 = (long)blockIdx.x*128 + wm*64 + m*16 + lq*4;
    #pragma unroll
    for (int n=0;n<4;n++){
      int gc = blockIdx.y*128 + wn*64 + n*16 + lr;
      float bb = bias ? bias[gz*sBias + gc] : 0.0f;
      #pragma unroll
      for (int i=0;i<4;i++){
        long gr = gr0 + i;
        if (gr < M){
          float v = acc[m][n][i] + bb;
          if (Cf) Cf[gz*sCf + gr*(long)N + gc] = v;
          if (Cb) Cb[gz*sCb + gr*(long)N + gc] = f2b(v);
        }
      }
    }
  }
}

// --------------- bucket-centric GCN aggregation ----------------
// block = (bucket b, graph g): 64 nodes, LDS f32 acc, entries (c_low<<16 | r)
__global__ __launch_bounds__(256) void agg2_k(
    const u16* __restrict__ xw, long sXW,
    const u32* __restrict__ temp, long sT,
    const int* __restrict__ off, long sO,
    const float* __restrict__ dinv, long sD,
    const float* __restrict__ bias, long sBias,
    float* __restrict__ outF, long sOF,
    u16* __restrict__ outB, long sOB,
    int relu)
{
  __shared__ float acc[64*HD];
  int b=blockIdx.x, g=blockIdx.y;
  int t=threadIdx.x, lane=t&63, w=t>>6;
  #pragma unroll
  for(int i=0;i<32;i++) acc[t + i*256]=0.f;
  __syncthreads();
  const u32* xp = (const u32*)(xw + (long)g*sXW);
  const u32* tp = temp + (long)g*sT;
  const float* dv = dinv + (long)g*sD;
  const int* offg = off + (long)g*sO;
  int s=offg[b*CH], e=offg[(b+1)*CH];
  int cnt = e - s;
  int per = (cnt+3)>>2;
  int i0 = s + w*per;
  int i1 = min(i0+per, e);
  int i = i0;
  for(; i+4<=i1; i+=4){
    u32 t0=tp[i], t1=tp[i+1], t2=tp[i+2], t3=tp[i+3];
    int r0=t0&0xFFFF, r1=t1&0xFFFF, r2=t2&0xFFFF, r3=t3&0xFFFF;
    float w0=dv[r0], w1=dv[r1], w2=dv[r2], w3=dv[r3];
    u32 v0=xp[(long)r0*64+lane], v1=xp[(long)r1*64+lane];
    u32 v2=xp[(long)r2*64+lane], v3=xp[(long)r3*64+lane];
    int c0=(int)(t0>>16)*HD+lane*2, c1=(int)(t1>>16)*HD+lane*2;
    int c2=(int)(t2>>16)*HD+lane*2, c3=(int)(t3>>16)*HD+lane*2;
    unsafeAtomicAdd(&acc[c0],   w0*b2f((u16)v0));
    unsafeAtomicAdd(&acc[c0+1], w0*b2f((u16)(v0>>16)));
    unsafeAtomicAdd(&acc[c1],   w1*b2f((u16)v1));
    unsafeAtomicAdd(&acc[c1+1], w1*b2f((u16)(v1>>16)));
    unsafeAtomicAdd(&acc[c2],   w2*b2f((u16)v2));
    unsafeAtomicAdd(&acc[c2+1], w2*b2f((u16)(v2>>16)));
    unsafeAtomicAdd(&acc[c3],   w3*b2f((u16)v3));
    unsafeAtomicAdd(&acc[c3+1], w3*b2f((u16)(v3>>16)));
  }
  for(; i<i1; ++i){
    u32 t0=tp[i];
    int r0=t0&0xFFFF;
    float w0=dv[r0];
    u32 v0=xp[(long)r0*64+lane];
    int c0=(int)(t0>>16)*HD+lane*2;
    unsafeAtomicAdd(&acc[c0],   w0*b2f((u16)v0));
    unsafeAtomicAdd(&acc[c0+1], w0*b2f((u16)(v0>>16)));
  }
  __syncthreads();
  for(int n=w;n<64;n+=4){
    int c=b*64+n;
    float dc=dv[c];
    u32 v=xp[(long)c*64+lane];
    float ax=(acc[n*HD+lane*2]   + dc*b2f((u16)v))     *dc + bias[g*sBias+lane*2];
    float ay=(acc[n*HD+lane*2+1] + dc*b2f((u16)(v>>16)))*dc + bias[g*sBias+lane*2+1];
    if(relu){ ax=fmaxf(ax,0.f); ay=fmaxf(ay,0.f); }
    if(outF) ((float2*)(outF + (long)g*sOF + (long)c*HD))[lane]=make_float2(ax,ay);
    if(outB) ((u32*)(outB + (long)g*sOB))[(long)c*64+lane]=(u32)f2b(ax)|((u32)f2b(ay)<<16);
  }
}

// --------------- closed-form h2 = conv2(conv1(0)) ----------------
__global__ void yvec_k(const float* __restrict__ b1, const float* __restrict__ W2,
                       float* __restrict__ y){
  int n=threadIdx.x;   // 128 threads
  float s=0.f;
  for(int k=0;k<HD;k++) s += b1[k]*W2[(long)k*HD+n];
  y[n]=s;
}

__global__ __launch_bounds__(64) void h2_k(const u32* __restrict__ temp, const int* __restrict__ off,
                                           const float* __restrict__ dinv, const float* __restrict__ y,
                                           const float* __restrict__ b2, float* __restrict__ outF){
  int b=blockIdx.x, lane=threadIdx.x;
  __shared__ float sacc[64];
  sacc[lane]=0.f;
  __syncthreads();
  int s=off[b*CH], e=off[(b+1)*CH];
  for(int i=s+lane;i<e;i+=64){
    u32 t=temp[i];
    unsafeAtomicAdd(&sacc[t>>16], dinv[t&0xFFFF]);
  }
  __syncthreads();
  float y0=y[2*lane], y1=y[2*lane+1], bb0=b2[2*lane], bb1=b2[2*lane+1];
  for(int n=0;n<64;n++){
    int c=b*64+n;
    float dc=dinv[c];
    float f=dc*dc+dc*sacc[n];
    ((float2*)(outF+(long)c*HD))[lane]=make_float2(y0*f+bb0, y1*f+bb1);
  }
}

// --------------- elementwise ----------------
__global__ void ew_neg2(const float4* __restrict__ a, const float4* __restrict__ b,
                        u16* __restrict__ ob, int n4){
  int i = blockIdx.x*256 + threadIdx.x;
  if (i >= n4) return;
  float4 va = a[i], vb = b[i];
  float x0 = -(va.x+vb.x), x1 = -(va.y+vb.y), x2 = -(va.z+vb.z), x3 = -(va.w+vb.w);
  ((uint2*)ob)[i] = make_uint2((u32)f2b(x0) | ((u32)f2b(x1)<<16),
                               (u32)f2b(x2) | ((u32)f2b(x3)<<16));
}

__global__ void ew_fin(const float4* __restrict__ a, const float4* __restrict__ b,
                       float4* __restrict__ of, u16* __restrict__ ob, int n4){
  int i = blockIdx.x*256 + threadIdx.x;
  if (i >= n4) return;
  float4 va = a[i], vb = b[i];
  float4 v = make_float4(va.x+vb.x, va.y+vb.y, va.z+vb.z, va.w+vb.w);
  of[i] = v;
  ((uint2*)ob)[i] = make_uint2((u32)f2b(v.x) | ((u32)f2b(v.y)<<16),
                               (u32)f2b(v.z) | ((u32)f2b(v.w)<<16));
}

__global__ void softmax_k(float* __restrict__ d, int rows){
  int wid = (blockIdx.x*256 + threadIdx.x) >> 6;
  if (wid >= rows) return;
  int lane = threadIdx.x & 63;
  float4* p = (float4*)(d + (long)wid*FD);
  float4 v = p[lane];
  float m = fmaxf(fmaxf(v.x, v.y), fmaxf(v.z, v.w));
  #pragma unroll
  for (int o=32; o; o>>=1) m = fmaxf(m, __shfl_xor(m, o, 64));
  float e0 = __expf(v.x-m), e1 = __expf(v.y-m), e2 = __expf(v.z-m), e3 = __expf(v.w-m);
  float s = e0+e1+e2+e3;
  #pragma unroll
  for (int o=32; o; o>>=1) s += __shfl_xor(s, o, 64);
  float inv = 1.0f/s;
  p[lane] = make_float4(e0*inv, e1*inv, e2*inv, e3*inv);
}

// ===================== host =====================
extern "C" void kernel_launch(void* const* d_in, const int* in_sizes, int n_in,
                              void* d_out, int out_size, void* d_ws, size_t ws_size,
                              hipStream_t stream)
{
  const float* x    = (const float*)d_in[0];
  const int*   ei   = (const int*)  d_in[1];
  const float* fc1W = (const float*)d_in[2];
  const float* fc1b = (const float*)d_in[3];
  const float* c1W  = (const float*)d_in[4];
  const float* c1b  = (const float*)d_in[5];
  const float* c2W  = (const float*)d_in[6];
  const float* c2b  = (const float*)d_in[7];
  const float* d1W  = (const float*)d_in[8];
  const float* d1b  = (const float*)d_in[9];
  const float* d2W  = (const float*)d_in[10];
  const float* d2b  = (const float*)d_in[11];
  const float* fc2W = (const float*)d_in[12];
  const float* fc2b = (const float*)d_in[13];
  (void)in_sizes; (void)n_in; (void)out_size; (void)ws_size;

  float* out  = (float*)d_out;
  float* O_pre = out;
  float* O_enc = out + (long)NG*NH;
  float* O_h   = out + 2L*NG*NH;
  float* O_fin = out + 3L*NG*NH;
  float* O_ls  = O_fin + NH;

  char* p = (char*)d_ws;
  auto alloc = [&](size_t bytes)->void*{
    void* r = (void*)p; p += (bytes + 255) & ~(size_t)255; return r;
  };
  u16* bfA    = (u16*)alloc((size_t)NG*NH*2);
  u16* bfXW   = (u16*)alloc((size_t)NG*NH*2);
  u16* wt_fc1 = (u16*)alloc((size_t)NG*FD*HD*2);
  u16* wt_c1  = (u16*)alloc((size_t)NG*HD*HD*2);
  u16* wt_c2  = (u16*)alloc((size_t)NG*HD*HD*2);
  u16* wt_d1  = (u16*)alloc((size_t)NG*HD*HD*2);
  u16* wt_d2  = (u16*)alloc((size_t)NG*HD*HD*2);
  u16* wt_fc2 = (u16*)alloc((size_t)HD*FD*2);
  u32*  temp  = (u32*) alloc((size_t)NG*ED*4);
  int*  hist  = (int*) alloc((size_t)NG*TOT*4);
  int*  off   = (int*) alloc((size_t)NG*OFFS*4);
  float* dinv = (float*)alloc((size_t)NG*NV*4);
  float* yv   = (float*)alloc((size_t)HD*4);

  // ---- binning (replaces CSR build; reused by all convs) ----
  hist_k<<<dim3(CH,NG), 256, 0, stream>>>(ei, hist);
  scan2_k<<<NG, 1024, 0, stream>>>(hist, off);
  scat_k<<<dim3(CH,NG), 256, 0, stream>>>(ei, off, temp);
  deg_k<<<dim3(NB,NG), 64, 0, stream>>>(temp, off, dinv);

  // ---- weight transposes to [N][K] bf16 ----
  tr_k<<<(NG*FD*HD+255)/256, 256, 0, stream>>>(fc1W, wt_fc1, FD, HD, (long)NG*FD*HD);
  tr_k<<<(NG*HD*HD+255)/256, 256, 0, stream>>>(c1W, wt_c1, HD, HD, (long)NG*HD*HD);
  tr_k<<<(NG*HD*HD+255)/256, 256, 0, stream>>>(c2W, wt_c2, HD, HD, (long)NG*HD*HD);
  tr_k<<<(NG*HD*HD+255)/256, 256, 0, stream>>>(d1W, wt_d1, HD, HD, (long)NG*HD*HD);
  tr_k<<<(NG*HD*HD+255)/256, 256, 0, stream>>>(d2W, wt_d2, HD, HD, (long)NG*HD*HD);
  tr_k<<<(HD*FD+255)/256, 256, 0, stream>>>(fc2W, wt_fc2, HD, FD, (long)HD*FD);

  dim3 gB((NV+127)/128, 1, NG);
  dim3 g1((NV+127)/128, 1, 1);
  dim3 g2((NV+127)/128, 2, 1);

  // ---- encoder (all 3 graphs batched) ----
  gemm_k<1><<<gB, 256, 0, stream>>>(x, (long)NV*FD, wt_fc1, (long)FD*HD, fc1b, HD,
                                    O_pre, NH, bfA, NH, NV, HD, FD);
  gemm_k<0><<<gB, 256, 0, stream>>>(bfA, NH, wt_c1, (long)HD*HD, nullptr, 0,
                                    nullptr, 0, bfXW, NH, NV, HD, HD);
  agg2_k<<<dim3(NB,NG), 256, 0, stream>>>(bfXW, NH, temp, ED, off, OFFS, dinv, NV,
                                          c1b, HD, nullptr, 0, bfA, NH, 0);
  gemm_k<0><<<gB, 256, 0, stream>>>(bfA, NH, wt_c2, (long)HD*HD, nullptr, 0,
                                    nullptr, 0, bfXW, NH, NV, HD, HD);
  agg2_k<<<dim3(NB,NG), 256, 0, stream>>>(bfXW, NH, temp, ED, off, OFFS, dinv, NV,
                                          c2b, HD, O_enc, NH, nullptr, 0, 1);

  // ---- closed-form h2 = conv2(conv1(0)) for graph 2 ----
  yvec_k<<<1, HD, 0, stream>>>(d1b + 2*HD, d2W + 2L*HD*HD, yv);
  h2_k<<<NB, 64, 0, stream>>>(temp + 2L*ED, off + 2L*OFFS, dinv + 2L*NV, yv,
                              d2b + 2*HD, O_h + 2L*NH);

  // ---- decoder graphs 0,1 (sequential dependency) ----
  for (int i=0; i<2; i++){
    if (i == 0) ew_neg2<<<NH/4/256, 256, 0, stream>>>((const float4*)O_enc, (const float4*)(O_enc+NH), bfA, NH/4);
    else        ew_neg2<<<NH/4/256, 256, 0, stream>>>((const float4*)(O_enc+NH), (const float4*)O_h, bfA, NH/4);

    gemm_k<0><<<g1, 256, 0, stream>>>(bfA, 0, wt_d1 + (long)i*HD*HD, 0, nullptr, 0,
                                      nullptr, 0, bfXW, 0, NV, HD, HD);
    agg2_k<<<dim3(NB,1), 256, 0, stream>>>(bfXW, 0, temp + (long)i*ED, 0, off + (long)i*OFFS, 0,
                                           dinv + (long)i*NV, 0, d1b + i*HD, 0,
                                           nullptr, 0, bfA, 0, 0);
    gemm_k<0><<<g1, 256, 0, stream>>>(bfA, 0, wt_d2 + (long)i*HD*HD, 0, nullptr, 0,
                                      nullptr, 0, bfXW, 0, NV, HD, HD);
    agg2_k<<<dim3(NB,1), 256, 0, stream>>>(bfXW, 0, temp + (long)i*ED, 0, off + (long)i*OFFS, 0,
                                           dinv + (long)i*NV, 0, d2b + i*HD, 0,
                                           O_h + (long)i*NH, 0, nullptr, 0, 0);
  }

  // ---- fin + fc2 + softmax ----
  ew_fin<<<NH/4/256, 256, 0, stream>>>((const float4*)O_h, (const float4*)(O_h+NH),
                                       (float4*)O_fin, bfA, NH/4);
  gemm_k<0><<<g2, 256, 0, stream>>>(bfA, 0, wt_fc2, 0, fc2b, 0,
                                    O_ls, 0, nullptr, 0, NV, FD, HD);
  softmax_k<<<NV/4, 256, 0, stream>>>(O_ls, NV);
}

// Round 3
// 722.810 us; speedup vs baseline: 7.1509x; 7.1509x over previous
//
#include <hip/hip_runtime.h>
#include <hip/hip_bf16.h>

#define NV 40000
#define FD 256
#define HD 128
#define ED 640000
#define NG 3
#define NH (NV*HD)

#define CH  64            // chunks per graph
#define EPC (ED/CH)       // 10000 edges per chunk
#define NB  625           // buckets of 64 nodes
#define TOT (NB*CH)
#define OFFS (TOT+2)

typedef unsigned short u16;
typedef unsigned int   u32;
typedef __attribute__((ext_vector_type(8))) u16    u16x8;
typedef __attribute__((ext_vector_type(8))) __bf16 bf16x8;
typedef __attribute__((ext_vector_type(4))) float  f32x4;

__device__ inline u16 f2b(float f){ __bf16 h = (__bf16)f; return __builtin_bit_cast(u16, h); }
__device__ inline float b2f(u16 u){ u32 x = ((u32)u)<<16; return __builtin_bit_cast(float, x); }

// ---------------- binning: hist -> scan -> scatter -> bucket sort ----------------
__global__ __launch_bounds__(256) void hist_k(const int* __restrict__ ei, int* __restrict__ hist){
  int ch = blockIdx.x, g = blockIdx.y, t = threadIdx.x;
  __shared__ int h[NB];
  for (int i=t;i<NB;i+=256) h[i]=0;
  __syncthreads();
  const int* cc = ei + (long)g*2*ED + ED + ch*EPC;
  for (int j=t;j<EPC;j+=256) atomicAdd(&h[cc[j]>>6],1);
  __syncthreads();
  int* hg = hist + (long)g*TOT;
  for (int b=t;b<NB;b+=256) hg[b*CH+ch]=h[b];
}

__global__ void scan2_k(const int* __restrict__ hist, int* __restrict__ off){
  int g = blockIdx.x;
  const int* src = hist + (long)g*TOT;
  int* dst = off + (long)g*OFFS;
  __shared__ int wsum[16];
  __shared__ int carrySh;
  int tid=threadIdx.x, lane=tid&63, wv=tid>>6;
  if (tid==0) carrySh=0;
  __syncthreads();
  for (int base=0;base<TOT;base+=1024){
    int i=base+tid;
    int v=(i<TOT)?src[i]:0;
    int s=v;
    #pragma unroll
    for (int d=1;d<64;d<<=1){ int t2=__shfl_up(s,d,64); if(lane>=d) s+=t2; }
    if(lane==63) wsum[wv]=s;
    __syncthreads();
    int carry=carrySh;
    if(wv==0){
      int t3=(lane<16)?wsum[lane]:0;
      #pragma unroll
      for(int d=1;d<16;d<<=1){ int u=__shfl_up(t3,d,64); if(lane>=d) t3+=u; }
      if(lane<16) wsum[lane]=t3;
    }
    __syncthreads();
    int woff=(wv>0)?wsum[wv-1]:0;
    int incl=s+woff+carry;
    if(i<TOT){ dst[i]=incl-v; if(i==TOT-1) dst[TOT]=incl; }
    __syncthreads();
    if(tid==1023) carrySh=incl;
    __syncthreads();
  }
}

__global__ __launch_bounds__(256) void scat_k(const int* __restrict__ ei, const int* __restrict__ off,
                                              u32* __restrict__ temp){
  int ch=blockIdx.x, g=blockIdx.y, t=threadIdx.x;
  __shared__ int cur[NB];
  const int* offg = off + (long)g*OFFS;
  for (int b=t;b<NB;b+=256) cur[b]=offg[b*CH+ch];
  __syncthreads();
  const int* rr = ei + (long)g*2*ED + ch*EPC;
  const int* cc = rr + ED;
  u32* tg = temp + (long)g*ED;
  for (int j=t;j<EPC;j+=256){
    int r=rr[j], c=cc[j];
    int pos=atomicAdd(&cur[c>>6],1);
    tg[pos]=((u32)(c&63)<<16)|(u32)r;
  }
}

// bucket-local counting sort -> u16 CSR + cptr + dinv
__global__ __launch_bounds__(256) void sort_k(const u32* __restrict__ temp, const int* __restrict__ off,
                                              u16* __restrict__ csr, int* __restrict__ cptr,
                                              float* __restrict__ dinv){
  int b=blockIdx.x, g=blockIdx.y, t=threadIdx.x;
  __shared__ int cnt[64];
  __shared__ int cur[64];
  if (t<64) cnt[t]=0;
  __syncthreads();
  const u32* tg = temp + (long)g*ED;
  const int* offg = off + (long)g*OFFS;
  int s=offg[b*CH], e=offg[(b+1)*CH];
  for (int i=s+t;i<e;i+=256) atomicAdd(&cnt[tg[i]>>16],1);
  __syncthreads();
  if (t<64){
    int v=cnt[t];
    int sc=v;
    #pragma unroll
    for (int d=1;d<64;d<<=1){ int u=__shfl_up(sc,d,64); if(t>=d) sc+=u; }
    int st = s + sc - v;
    cur[t]=st;
    cptr[(long)g*(NV+1) + b*64 + t] = st;
    if (b==NB-1 && t==63) cptr[(long)g*(NV+1)+NV] = e;
    dinv[(long)g*NV + b*64 + t] = rsqrtf((float)v+1.0f);
  }
  __syncthreads();
  u16* cg = csr + (long)g*ED;
  for (int i=s+t;i<e;i+=256){
    u32 tt=tg[i];
    int pos=atomicAdd(&cur[tt>>16],1);
    cg[pos]=(u16)(tt&0xFFFF);
  }
}

// ---------------- all weight transposes + yvec in one launch ----------------
__device__ inline void tr_seg(const float* __restrict__ src, u16* __restrict__ dst,
                              int K, int NN, long idx, long total){
  if (idx>=total) return;
  long per=(long)K*NN; long mat=idx/per; long rem=idx-mat*per;
  int k=(int)(rem/NN), c=(int)(rem-(long)k*NN);
  dst[mat*per+(long)c*K+k]=f2b(src[idx]);
}

__global__ __launch_bounds__(256) void trall_k(
    const float* fc1W, const float* c1W, const float* c2W,
    const float* d1W, const float* d2W, const float* fc2W,
    u16* w_fc1, u16* w_c1, u16* w_c2, u16* w_d1, u16* w_d2, u16* w_fc2,
    const float* b1g2, const float* W2g2, float* yv)
{
  int blk=blockIdx.x, t=threadIdx.x;
  if (blk < 384)       tr_seg(fc1W, w_fc1, FD, HD, (long)blk*256+t,        (long)NG*FD*HD);
  else if (blk < 576)  tr_seg(c1W,  w_c1,  HD, HD, (long)(blk-384)*256+t,  (long)NG*HD*HD);
  else if (blk < 768)  tr_seg(c2W,  w_c2,  HD, HD, (long)(blk-576)*256+t,  (long)NG*HD*HD);
  else if (blk < 960)  tr_seg(d1W,  w_d1,  HD, HD, (long)(blk-768)*256+t,  (long)NG*HD*HD);
  else if (blk < 1152) tr_seg(d2W,  w_d2,  HD, HD, (long)(blk-960)*256+t,  (long)NG*HD*HD);
  else if (blk < 1280) tr_seg(fc2W, w_fc2, HD, FD, (long)(blk-1152)*256+t, (long)HD*FD);
  else if (t < HD){
    float s=0.f;
    for (int k=0;k<HD;k++) s += b1g2[k]*W2g2[(long)k*HD+t];
    yv[t]=s;
  }
}

// --------------- bf16 MFMA GEMM: C = A @ Bt^T (+bias, +row-scaled bf16 out) ------
// MODE 0: A bf16 | 1: A f32 | 2: A = -(A0+A1) f32 | 3: A = A0+A1 f32
template<int MODE>
__global__ __launch_bounds__(256) void gemm_k(
    const void* __restrict__ A_, const void* __restrict__ A2_, long sA,
    const u16* __restrict__ Bt, long sB,
    const float* __restrict__ bias, long sBias,
    const float* __restrict__ scale, long sSc,
    float* __restrict__ Cf, long sCf,
    u16* __restrict__ Cb, long sCb,
    int M, int N, int K)
{
  __shared__ __align__(16) u16 lsA[128*64];
  __shared__ __align__(16) u16 lsB[128*64];
  const int gz = blockIdx.z;
  const float* Af  = (const float*)A_  + (long)gz*sA;
  const float* Af2 = (const float*)A2_ + (long)gz*sA;
  const u16*   Ab  = (const u16*)  A_  + (long)gz*sA;
  const u16* Bp = Bt + (long)gz*sB;
  const int t = threadIdx.x;
  const int lane = t & 63, wv = t >> 6, wm = wv >> 1, wn = wv & 1;
  const int lr = lane & 15, lq = lane >> 4;
  const int ar = t >> 1, ah = t & 1;
  const long grow = (long)blockIdx.x*128 + ar;
  const int colB = blockIdx.y*128 + ar;

  f32x4 acc[4][4];
  #pragma unroll
  for (int m=0;m<4;m++)
    #pragma unroll
    for (int n=0;n<4;n++) acc[m][n] = (f32x4)(0.0f);

  for (int k0=0; k0<K; k0+=64){
    if (k0) __syncthreads();
    u16x8 av[4];
    if (grow < M){
      if (MODE==0){
        const u16x8* s = (const u16x8*)(Ab + grow*(long)K + k0 + ah*32);
        #pragma unroll
        for (int i=0;i<4;i++) av[i] = s[i];
      } else if (MODE==1){
        const float4* s = (const float4*)(Af + grow*(long)K + k0 + ah*32);
        #pragma unroll
        for (int i=0;i<4;i++){
          float4 v0 = s[i*2], v1 = s[i*2+1];
          u16x8 w;
          w[0]=f2b(v0.x); w[1]=f2b(v0.y); w[2]=f2b(v0.z); w[3]=f2b(v0.w);
          w[4]=f2b(v1.x); w[5]=f2b(v1.y); w[6]=f2b(v1.z); w[7]=f2b(v1.w);
          av[i] = w;
        }
      } else {
        const float4* s0 = (const float4*)(Af  + grow*(long)K + k0 + ah*32);
        const float4* s1 = (const float4*)(Af2 + grow*(long)K + k0 + ah*32);
        #pragma unroll
        for (int i=0;i<4;i++){
          float4 a0 = s0[i*2], a1 = s0[i*2+1];
          float4 b0 = s1[i*2], b1 = s1[i*2+1];
          float x0,x1,x2,x3,y0,y1,y2,y3;
          if (MODE==2){
            x0=-(a0.x+b0.x); x1=-(a0.y+b0.y); x2=-(a0.z+b0.z); x3=-(a0.w+b0.w);
            y0=-(a1.x+b1.x); y1=-(a1.y+b1.y); y2=-(a1.z+b1.z); y3=-(a1.w+b1.w);
          } else {
            x0=a0.x+b0.x; x1=a0.y+b0.y; x2=a0.z+b0.z; x3=a0.w+b0.w;
            y0=a1.x+b1.x; y1=a1.y+b1.y; y2=a1.z+b1.z; y3=a1.w+b1.w;
          }
          u16x8 w;
          w[0]=f2b(x0); w[1]=f2b(x1); w[2]=f2b(x2); w[3]=f2b(x3);
          w[4]=f2b(y0); w[5]=f2b(y1); w[6]=f2b(y2); w[7]=f2b(y3);
          av[i] = w;
        }
      }
    } else {
      #pragma unroll
      for (int i=0;i<4;i++) av[i] = (u16x8)((u16)0);
    }
    #pragma unroll
    for (int i=0;i<4;i++){
      int q = ah*4 + i;
      *(u16x8*)&lsA[ar*64 + ((q ^ (ar&7))<<3)] = av[i];
    }
    {
      const u16x8* s = (const u16x8*)(Bp + (long)colB*K + k0 + ah*32);
      #pragma unroll
      for (int i=0;i<4;i++){
        int q = ah*4 + i;
        *(u16x8*)&lsB[ar*64 + ((q ^ (ar&7))<<3)] = s[i];
      }
    }
    __syncthreads();
    #pragma unroll
    for (int kk=0; kk<2; kk++){
      bf16x8 afr[4], bfr[4];
      #pragma unroll
      for (int m=0;m<4;m++){
        int r = wm*64 + m*16 + lr;
        int q = kk*4 + lq;
        afr[m] = __builtin_bit_cast(bf16x8, *(const u16x8*)&lsA[r*64 + ((q ^ (r&7))<<3)]);
      }
      #pragma unroll
      for (int n=0;n<4;n++){
        int r = wn*64 + n*16 + lr;
        int q = kk*4 + lq;
        bfr[n] = __builtin_bit_cast(bf16x8, *(const u16x8*)&lsB[r*64 + ((q ^ (r&7))<<3)]);
      }
      #pragma unroll
      for (int m=0;m<4;m++)
        #pragma unroll
        for (int n=0;n<4;n++)
          acc[m][n] = __builtin_amdgcn_mfma_f32_16x16x32_bf16(afr[m], bfr[n], acc[m][n], 0, 0, 0);
    }
  }
  #pragma unroll
  for (int m=0;m<4;m++){
    long gr0 = (long)blockIdx.x*128 + wm*64 + m*16 + lq*4;
    #pragma unroll
    for (int n=0;n<4;n++){
      int gc = blockIdx.y*128 + wn*64 + n*16 + lr;
      float bb = bias ? bias[gz*sBias + gc] : 0.0f;
      #pragma unroll
      for (int i=0;i<4;i++){
        long gr = gr0 + i;
        if (gr < M){
          float v = acc[m][n][i] + bb;
          if (Cf) Cf[gz*sCf + gr*(long)N + gc] = v;
          if (Cb){
            float sc = scale ? scale[gz*sSc + gr] : 1.0f;
            Cb[gz*sCb + gr*(long)N + gc] = f2b(v*sc);
          }
        }
      }
    }
  }
}

// --------------- GCN aggregation: wave per node, pre-scaled features z = dinv*xw --
// out[c] = dinv[c]*(z[c] + sum_in z[r]) + bias
__global__ __launch_bounds__(256) void agg3_k(
    const u16* __restrict__ xw, long sXW,
    const u16* __restrict__ csr, long sCsr,
    const int* __restrict__ cptr, long sCp,
    const float* __restrict__ dinv, long sD,
    const float* __restrict__ bias, long sBias,
    float* __restrict__ outF, long sOF,
    u16* __restrict__ outB, long sOB,
    int totWaves, int relu)
{
  int wid = (int)((blockIdx.x*256 + threadIdx.x) >> 6);
  if (wid >= totWaves) return;
  int lane = threadIdx.x & 63;
  int g = wid / NV;
  int c = wid - g*NV;
  const u32* xp = (const u32*)(xw + (long)g*sXW);
  const u16* cg = csr + (long)g*sCsr;
  const int* cp = cptr + (long)g*sCp;
  float dc = dinv[(long)g*sD + c];
  u32 u = xp[(long)c*64 + lane];
  float sx = b2f((u16)u), sy = b2f((u16)(u>>16));
  int j0 = cp[c], j1 = cp[c+1];
  int deg = j1 - j0;
  int idx = 0;
  if (lane < deg) idx = cg[j0 + lane];
  int kmax = min(deg, 64);
  int k = 0;
  for (; k+4<=kmax; k+=4){
    int r0=__shfl(idx,k,64), r1=__shfl(idx,k+1,64), r2=__shfl(idx,k+2,64), r3=__shfl(idx,k+3,64);
    u32 v0=xp[(long)r0*64+lane], v1=xp[(long)r1*64+lane];
    u32 v2=xp[(long)r2*64+lane], v3=xp[(long)r3*64+lane];
    sx += b2f((u16)v0); sy += b2f((u16)(v0>>16));
    sx += b2f((u16)v1); sy += b2f((u16)(v1>>16));
    sx += b2f((u16)v2); sy += b2f((u16)(v2>>16));
    sx += b2f((u16)v3); sy += b2f((u16)(v3>>16));
  }
  for (; k<kmax; ++k){
    int r=__shfl(idx,k,64);
    u32 v=xp[(long)r*64+lane];
    sx += b2f((u16)v); sy += b2f((u16)(v>>16));
  }
  for (int j=j0+64; j<j1; ++j){
    int r=cg[j];
    u32 v=xp[(long)r*64+lane];
    sx += b2f((u16)v); sy += b2f((u16)(v>>16));
  }
  float ox = dc*sx + bias[g*sBias + lane*2];
  float oy = dc*sy + bias[g*sBias + lane*2 + 1];
  if (relu){ ox=fmaxf(ox,0.f); oy=fmaxf(oy,0.f); }
  if (outF) ((float2*)(outF + (long)g*sOF + (long)c*HD))[lane] = make_float2(ox, oy);
  if (outB) ((u32*)(outB + (long)g*sOB))[(long)c*64 + lane] = (u32)f2b(ox) | ((u32)f2b(oy)<<16);
}

// --------------- closed-form h2 = conv2(conv1(0)) ----------------
__global__ __launch_bounds__(64) void h2_k(const u32* __restrict__ temp, const int* __restrict__ off,
                                           const float* __restrict__ dinv, const float* __restrict__ y,
                                           const float* __restrict__ b2, float* __restrict__ outF){
  int b=blockIdx.x, lane=threadIdx.x;
  __shared__ float sacc[64];
  sacc[lane]=0.f;
  __syncthreads();
  int s=off[b*CH], e=off[(b+1)*CH];
  for(int i=s+lane;i<e;i+=64){
    u32 t=temp[i];
    unsafeAtomicAdd(&sacc[t>>16], dinv[t&0xFFFF]);
  }
  __syncthreads();
  float y0=y[2*lane], y1=y[2*lane+1], bb0=b2[2*lane], bb1=b2[2*lane+1];
  for(int n=0;n<64;n++){
    int c=b*64+n;
    float dc=dinv[c];
    float f=dc*dc+dc*sacc[n];
    ((float2*)(outF+(long)c*HD))[lane]=make_float2(y0*f+bb0, y1*f+bb1);
  }
}

// --------------- elementwise fin (f32 only) + softmax ----------------
__global__ void ew_add(const float4* __restrict__ a, const float4* __restrict__ b,
                       float4* __restrict__ of, int n4){
  int i = blockIdx.x*256 + threadIdx.x;
  if (i >= n4) return;
  float4 va = a[i], vb = b[i];
  of[i] = make_float4(va.x+vb.x, va.y+vb.y, va.z+vb.z, va.w+vb.w);
}

__global__ void softmax_k(float* __restrict__ d, int rows){
  int wid = (blockIdx.x*256 + threadIdx.x) >> 6;
  if (wid >= rows) return;
  int lane = threadIdx.x & 63;
  float4* p = (float4*)(d + (long)wid*FD);
  float4 v = p[lane];
  float m = fmaxf(fmaxf(v.x, v.y), fmaxf(v.z, v.w));
  #pragma unroll
  for (int o=32; o; o>>=1) m = fmaxf(m, __shfl_xor(m, o, 64));
  float e0 = __expf(v.x-m), e1 = __expf(v.y-m), e2 = __expf(v.z-m), e3 = __expf(v.w-m);
  float s = e0+e1+e2+e3;
  #pragma unroll
  for (int o=32; o; o>>=1) s += __shfl_xor(s, o, 64);
  float inv = 1.0f/s;
  p[lane] = make_float4(e0*inv, e1*inv, e2*inv, e3*inv);
}

// ===================== host =====================
extern "C" void kernel_launch(void* const* d_in, const int* in_sizes, int n_in,
                              void* d_out, int out_size, void* d_ws, size_t ws_size,
                              hipStream_t stream)
{
  const float* x    = (const float*)d_in[0];
  const int*   ei   = (const int*)  d_in[1];
  const float* fc1W = (const float*)d_in[2];
  const float* fc1b = (const float*)d_in[3];
  const float* c1W  = (const float*)d_in[4];
  const float* c1b  = (const float*)d_in[5];
  const float* c2W  = (const float*)d_in[6];
  const float* c2b  = (const float*)d_in[7];
  const float* d1W  = (const float*)d_in[8];
  const float* d1b  = (const float*)d_in[9];
  const float* d2W  = (const float*)d_in[10];
  const float* d2b  = (const float*)d_in[11];
  const float* fc2W = (const float*)d_in[12];
  const float* fc2b = (const float*)d_in[13];
  (void)in_sizes; (void)n_in; (void)out_size; (void)ws_size;

  float* out  = (float*)d_out;
  float* O_pre = out;
  float* O_enc = out + (long)NG*NH;
  float* O_h   = out + 2L*NG*NH;
  float* O_fin = out + 3L*NG*NH;
  float* O_ls  = O_fin + NH;

  char* p = (char*)d_ws;
  auto alloc = [&](size_t bytes)->void*{
    void* r = (void*)p; p += (bytes + 255) & ~(size_t)255; return r;
  };
  u16* bfA    = (u16*)alloc((size_t)NG*NH*2);
  u16* bfXW   = (u16*)alloc((size_t)NG*NH*2);
  u16* wt_fc1 = (u16*)alloc((size_t)NG*FD*HD*2);
  u16* wt_c1  = (u16*)alloc((size_t)NG*HD*HD*2);
  u16* wt_c2  = (u16*)alloc((size_t)NG*HD*HD*2);
  u16* wt_d1  = (u16*)alloc((size_t)NG*HD*HD*2);
  u16* wt_d2  = (u16*)alloc((size_t)NG*HD*HD*2);
  u16* wt_fc2 = (u16*)alloc((size_t)HD*FD*2);
  u32*  temp  = (u32*) alloc((size_t)NG*ED*4);
  u16*  csr   = (u16*) alloc((size_t)NG*ED*2);
  int*  cptr  = (int*) alloc((size_t)NG*(NV+1)*4);
  int*  hist  = (int*) alloc((size_t)NG*TOT*4);
  int*  off   = (int*) alloc((size_t)NG*OFFS*4);
  float* dinv = (float*)alloc((size_t)NG*NV*4);
  float* yv   = (float*)alloc((size_t)HD*4);

  // ---- binning + CSR (reused by all convs) ----
  hist_k<<<dim3(CH,NG), 256, 0, stream>>>(ei, hist);
  scan2_k<<<NG, 1024, 0, stream>>>(hist, off);
  scat_k<<<dim3(CH,NG), 256, 0, stream>>>(ei, off, temp);
  sort_k<<<dim3(NB,NG), 256, 0, stream>>>(temp, off, csr, cptr, dinv);

  // ---- weight transposes + yvec ----
  trall_k<<<1281, 256, 0, stream>>>(fc1W, c1W, c2W, d1W, d2W, fc2W,
                                    wt_fc1, wt_c1, wt_c2, wt_d1, wt_d2, wt_fc2,
                                    d1b + 2*HD, d2W + 2L*HD*HD, yv);

  dim3 gB((NV+127)/128, 1, NG);
  dim3 g1((NV+127)/128, 1, 1);
  dim3 g2((NV+127)/128, 2, 1);

  // ---- encoder (all 3 graphs batched) ----
  gemm_k<1><<<gB, 256, 0, stream>>>(x, nullptr, (long)NV*FD, wt_fc1, (long)FD*HD, fc1b, HD,
                                    nullptr, 0, O_pre, NH, bfA, NH, NV, HD, FD);
  gemm_k<0><<<gB, 256, 0, stream>>>(bfA, nullptr, NH, wt_c1, (long)HD*HD, nullptr, 0,
                                    dinv, NV, nullptr, 0, bfXW, NH, NV, HD, HD);
  agg3_k<<<NG*NV/4, 256, 0, stream>>>(bfXW, NH, csr, ED, cptr, NV+1, dinv, NV,
                                      c1b, HD, nullptr, 0, bfA, NH, NG*NV, 0);
  gemm_k<0><<<gB, 256, 0, stream>>>(bfA, nullptr, NH, wt_c2, (long)HD*HD, nullptr, 0,
                                    dinv, NV, nullptr, 0, bfXW, NH, NV, HD, HD);
  agg3_k<<<NG*NV/4, 256, 0, stream>>>(bfXW, NH, csr, ED, cptr, NV+1, dinv, NV,
                                      c2b, HD, O_enc, NH, nullptr, 0, NG*NV, 1);

  // ---- closed-form h2 for graph 2 ----
  h2_k<<<NB, 64, 0, stream>>>(temp + 2L*ED, off + 2L*OFFS, dinv + 2L*NV, yv,
                              d2b + 2*HD, O_h + 2L*NH);

  // ---- decoder graphs 0,1 (sequential) ----
  for (int i=0; i<2; i++){
    const float* P0 = (i==0) ? O_enc        : (O_enc + NH);
    const float* P1 = (i==0) ? (O_enc + NH) : O_h;
    gemm_k<2><<<g1, 256, 0, stream>>>(P0, P1, 0, wt_d1 + (long)i*HD*HD, 0, nullptr, 0,
                                      dinv + (long)i*NV, 0, nullptr, 0, bfXW, 0, NV, HD, HD);
    agg3_k<<<NV/4, 256, 0, stream>>>(bfXW, 0, csr + (long)i*ED, 0, cptr + (long)i*(NV+1), 0,
                                     dinv + (long)i*NV, 0, d1b + i*HD, 0,
                                     nullptr, 0, bfA, 0, NV, 0);
    gemm_k<0><<<g1, 256, 0, stream>>>(bfA, nullptr, 0, wt_d2 + (long)i*HD*HD, 0, nullptr, 0,
                                      dinv + (long)i*NV, 0, nullptr, 0, bfXW, 0, NV, HD, HD);
    agg3_k<<<NV/4, 256, 0, stream>>>(bfXW, 0, csr + (long)i*ED, 0, cptr + (long)i*(NV+1), 0,
                                     dinv + (long)i*NV, 0, d2b + i*HD, 0,
                                     O_h + (long)i*NH, 0, nullptr, 0, NV, 0);
  }

  // ---- fin (f32 out) + fc2 (A = h0+h1 fused) + softmax ----
  ew_add<<<NH/4/256, 256, 0, stream>>>((const float4*)O_h, (const float4*)(O_h+NH),
                                       (float4*)O_fin, NH/4);
  gemm_k<3><<<g2, 256, 0, stream>>>(O_h, O_h + NH, 0, wt_fc2, 0, fc2b, 0,
                                    nullptr, 0, O_ls, 0, nullptr, 0, NV, FD, HD);
  softmax_k<<<NV/4, 256, 0, stream>>>(O_ls, NV);
}

// Round 5
// 603.733 us; speedup vs baseline: 8.5613x; 1.1972x over previous
//
#include <hip/hip_runtime.h>
#include <hip/hip_bf16.h>

#define NV 40000
#define FD 256
#define HD 128
#define ED 640000
#define NG 3
#define NH (NV*HD)

#define CH  64            // edge chunks per graph
#define EPC (ED/CH)       // 10000 edges per chunk
#define NB  625           // buckets of 64 nodes

typedef unsigned short u16;
typedef unsigned int   u32;
typedef __attribute__((ext_vector_type(8))) u16    u16x8;
typedef __attribute__((ext_vector_type(8))) __bf16 bf16x8;
typedef __attribute__((ext_vector_type(4))) float  f32x4;

__device__ inline u16 f2b(float f){ __bf16 h = (__bf16)f; return __builtin_bit_cast(u16, h); }
__device__ inline float b2f(u16 u){ u32 x = ((u32)u)<<16; return __builtin_bit_cast(float, x); }

// ---------------- binning: bucket hist -> tiny scan -> scatter -> bucket sort ----
__global__ __launch_bounds__(256) void histB_k(const int* __restrict__ ei, int* __restrict__ btot){
  int ch=blockIdx.x, g=blockIdx.y, t=threadIdx.x;
  __shared__ int h[NB];
  for (int i=t;i<NB;i+=256) h[i]=0;
  __syncthreads();
  const int* cc = ei + (long)g*2*ED + ED + ch*EPC;
  for (int j=t;j<EPC;j+=256) atomicAdd(&h[cc[j]>>6],1);
  __syncthreads();
  for (int b=t;b<NB;b+=256){ int v=h[b]; if(v) atomicAdd(&btot[g*NB+b], v); }
}

__global__ void scanB_k(const int* __restrict__ btot, int* __restrict__ base, int* __restrict__ gcur){
  __shared__ int wsum[16];
  int tid=threadIdx.x, lane=tid&63, wv=tid>>6;
  for (int g=0; g<NG; ++g){
    int v = (tid<NB)? btot[g*NB+tid] : 0;
    int s=v;
    #pragma unroll
    for (int d=1; d<64; d<<=1){ int u=__shfl_up(s,d,64); if(lane>=d) s+=u; }
    if (lane==63) wsum[wv]=s;
    __syncthreads();
    if (wv==0){
      int t3=(lane<16)?wsum[lane]:0;
      #pragma unroll
      for (int d=1; d<16; d<<=1){ int u=__shfl_up(t3,d,64); if(lane>=d) t3+=u; }
      if (lane<16) wsum[lane]=t3;
    }
    __syncthreads();
    int incl = s + (wv>0? wsum[wv-1]:0);
    if (tid<NB){
      base[g*(NB+1)+tid]=incl-v;
      gcur[g*NB+tid]=incl-v;
      if (tid==NB-1) base[g*(NB+1)+NB]=incl;
    }
    __syncthreads();
  }
}

__global__ __launch_bounds__(256) void scat_k(const int* __restrict__ ei, int* __restrict__ gcur,
                                              u32* __restrict__ temp){
  int ch=blockIdx.x, g=blockIdx.y, t=threadIdx.x;
  __shared__ int h[NB];
  __shared__ int cur[NB];
  for (int i=t;i<NB;i+=256) h[i]=0;
  __syncthreads();
  const int* rr = ei + (long)g*2*ED + ch*EPC;
  const int* cc = rr + ED;
  for (int j=t;j<EPC;j+=256) atomicAdd(&h[cc[j]>>6],1);
  __syncthreads();
  for (int b=t;b<NB;b+=256){ int v=h[b]; cur[b] = v? atomicAdd(&gcur[g*NB+b], v) : 0; }
  __syncthreads();
  u32* tg = temp + (long)g*ED;
  for (int j=t;j<EPC;j+=256){
    int r=rr[j], c=cc[j];
    int pos=atomicAdd(&cur[c>>6],1);
    tg[pos]=((u32)(c&63)<<16)|(u32)r;
  }
}

// bucket-local counting sort -> u16 CSR + cptr + dinv
__global__ __launch_bounds__(256) void sort_k(const u32* __restrict__ temp, const int* __restrict__ base,
                                              u16* __restrict__ csr, int* __restrict__ cptr,
                                              float* __restrict__ dinv){
  int b=blockIdx.x, g=blockIdx.y, t=threadIdx.x;
  __shared__ int cnt[64];
  __shared__ int cur[64];
  if (t<64) cnt[t]=0;
  __syncthreads();
  const u32* tg = temp + (long)g*ED;
  int s=base[g*(NB+1)+b], e=base[g*(NB+1)+b+1];
  for (int i=s+t;i<e;i+=256) atomicAdd(&cnt[tg[i]>>16],1);
  __syncthreads();
  if (t<64){
    int v=cnt[t];
    int sc=v;
    #pragma unroll
    for (int d=1;d<64;d<<=1){ int u=__shfl_up(sc,d,64); if(t>=d) sc+=u; }
    int st = s + sc - v;
    cur[t]=st;
    cptr[(long)g*(NV+1) + b*64 + t] = st;
    if (b==NB-1 && t==63) cptr[(long)g*(NV+1)+NV] = e;
    dinv[(long)g*NV + b*64 + t] = rsqrtf((float)v+1.0f);
  }
  __syncthreads();
  u16* cg = csr + (long)g*ED;
  for (int i=s+t;i<e;i+=256){
    u32 tt=tg[i];
    int pos=atomicAdd(&cur[tt>>16],1);
    cg[pos]=(u16)(tt&0xFFFF);
  }
}

// --------------- s = A_hat * 1  (per node) ----------------
__global__ __launch_bounds__(256) void svec_k(const u16* __restrict__ csr, const int* __restrict__ cptr,
                                              const float* __restrict__ dinv, float* __restrict__ sv,
                                              int totWaves){
  int wid=(int)((blockIdx.x*256+threadIdx.x)>>6);
  if (wid>=totWaves) return;
  int lane=threadIdx.x&63;
  int g=wid/NV, c=wid-g*NV;
  const u16* cg=csr+(long)g*ED;
  const int* cp=cptr+(long)g*(NV+1);
  const float* dv=dinv+(long)g*NV;
  int j0=cp[c], j1=cp[c+1];
  float sum=0.f;
  for (int j=j0+lane;j<j1;j+=64) sum+=dv[cg[j]];
  #pragma unroll
  for (int o=32;o;o>>=1) sum+=__shfl_xor(sum,o,64);
  if (lane==0){ float dc=dv[c]; sv[(long)g*NV+c]=dc*(dc+sum); }
}

// ---------------- transposes + fused W1*W2 products + t vectors ----------------
__device__ inline void tr_seg(const float* __restrict__ src, u16* __restrict__ dst,
                              int K, int NN, long idx, long total){
  if (idx>=total) return;
  long per=(long)K*NN; long mat=idx/per; long rem=idx-mat*per;
  int k=(int)(rem/NN), c=(int)(rem-(long)k*NN);
  dst[mat*per+(long)c*K+k]=f2b(src[idx]);
}

__global__ __launch_bounds__(256) void trall_k(
    const float* fc1W, const float* fc2W,
    const float* c1W, const float* c2W, const float* c1b,
    const float* d1W, const float* d2W, const float* d1b,
    u16* w_fc1, u16* w_fc2, u16* w_ce, u16* w_cd,
    float* t_enc, float* t_dec)
{
  int blk=blockIdx.x, t=threadIdx.x;
  if (blk < 384){            // fc1 transpose, 3 graphs
    tr_seg(fc1W, w_fc1, FD, HD, (long)blk*256+t, (long)NG*FD*HD);
  } else if (blk < 512){     // fc2 transpose
    tr_seg(fc2W, w_fc2, HD, FD, (long)(blk-384)*256+t, (long)HD*FD);
  } else if (blk < 832){     // 5 fused products Wc = W1*W2, output [N][K] bf16
    int bb=blk-512;
    int mat=bb>>6;
    int local=(bb&63)*256+t;
    int n=local>>7, k=local&127;
    const float* W1; const float* W2; u16* dst;
    if (mat<3){ W1=c1W+(long)mat*HD*HD; W2=c2W+(long)mat*HD*HD; dst=w_ce+(long)mat*HD*HD; }
    else { int md=mat-3; W1=d1W+(long)md*HD*HD; W2=d2W+(long)md*HD*HD; dst=w_cd+(long)md*HD*HD; }
    float s=0.f;
    for (int j=0;j<HD;j++) s += W1[k*HD+j]*W2[j*HD+n];
    dst[(long)n*HD+k]=f2b(s);
  } else {                   // t vectors: t = b1 @ W2  (6 of them, 768 elements total)
    for (int idx=t; idx<768; idx+=256){
      int which=idx>>7, n=idx&127;
      const float* b; const float* W; float* dst;
      if (which<3){ b=c1b+which*HD; W=c2W+(long)which*HD*HD; dst=t_enc+which*HD; }
      else { int w2=which-3; b=d1b+w2*HD; W=d2W+(long)w2*HD*HD; dst=t_dec+w2*HD; }
      float s=0.f;
      for (int k=0;k<HD;k++) s += b[k]*W[(long)k*HD+n];
      dst[n]=s;
    }
  }
}

// --------------- bf16 MFMA GEMM, 128x128 tile, BK=64 -----------------
// MODE: 0 = A bf16, 1 = A f32.
// EX: 0 plain (Cf opt, Cb=f2b(v*scale) opt)
//     1 dec0  (Cf=v; Cb=f2b(scale[row]*(-(v+Add[row][col]))))
//     2 dec1  (Cf=v; Cf2=v+Add[row][col])
// epilogue v = acc + biasCol + (svec? svec[row]*tvec[col] : 0); optional relu.
template<int MODE, int EX>
__global__ __launch_bounds__(256) void gemm_k(
    const void* __restrict__ A_, long sA,
    const u16* __restrict__ Bt, long sB,
    const float* __restrict__ biasCol, long sBias,
    const float* __restrict__ svec, long sS,
    const float* __restrict__ tvec,
    const float* __restrict__ scaleRow, long sSc,
    const float* __restrict__ Add,
    float* __restrict__ Cf, long sCf,
    float* __restrict__ Cf2,
    u16* __restrict__ Cb, long sCb,
    int M, int N, int K, int relu)
{
  __shared__ __align__(16) u16 lsA[128*64];
  __shared__ __align__(16) u16 lsB[128*64];
  const int gz = blockIdx.z;
  const float* Af = (const float*)A_ + (long)gz*sA;
  const u16*   Ab = (const u16*)  A_ + (long)gz*sA;
  const u16* Bp = Bt + (long)gz*sB;
  const int t = threadIdx.x;
  const int lane = t & 63, wv = t >> 6, wm = wv >> 1, wn = wv & 1;
  const int lr = lane & 15, lq = lane >> 4;
  const int ar = t >> 1, ah = t & 1;
  const long grow = (long)blockIdx.x*128 + ar;
  const int colB = blockIdx.y*128 + ar;

  f32x4 acc[4][4];
  #pragma unroll
  for (int m=0;m<4;m++)
    #pragma unroll
    for (int n=0;n<4;n++) acc[m][n] = (f32x4)(0.0f);

  for (int k0=0; k0<K; k0+=64){
    if (k0) __syncthreads();
    u16x8 av[4];
    if (grow < M){
      if (MODE==0){
        const u16x8* s = (const u16x8*)(Ab + grow*(long)K + k0 + ah*32);
        #pragma unroll
        for (int i=0;i<4;i++) av[i] = s[i];
      } else {
        const float4* s = (const float4*)(Af + grow*(long)K + k0 + ah*32);
        #pragma unroll
        for (int i=0;i<4;i++){
          float4 v0 = s[i*2], v1 = s[i*2+1];
          u16x8 w;
          w[0]=f2b(v0.x); w[1]=f2b(v0.y); w[2]=f2b(v0.z); w[3]=f2b(v0.w);
          w[4]=f2b(v1.x); w[5]=f2b(v1.y); w[6]=f2b(v1.z); w[7]=f2b(v1.w);
          av[i] = w;
        }
      }
    } else {
      #pragma unroll
      for (int i=0;i<4;i++) av[i] = (u16x8)((u16)0);
    }
    #pragma unroll
    for (int i=0;i<4;i++){
      int q = ah*4 + i;
      *(u16x8*)&lsA[ar*64 + ((q ^ (ar&7))<<3)] = av[i];
    }
    {
      const u16x8* s = (const u16x8*)(Bp + (long)colB*K + k0 + ah*32);
      #pragma unroll
      for (int i=0;i<4;i++){
        int q = ah*4 + i;
        *(u16x8*)&lsB[ar*64 + ((q ^ (ar&7))<<3)] = s[i];
      }
    }
    __syncthreads();
    #pragma unroll
    for (int kk=0; kk<2; kk++){
      bf16x8 afr[4], bfr[4];
      #pragma unroll
      for (int m=0;m<4;m++){
        int r = wm*64 + m*16 + lr;
        int q = kk*4 + lq;
        afr[m] = __builtin_bit_cast(bf16x8, *(const u16x8*)&lsA[r*64 + ((q ^ (r&7))<<3)]);
      }
      #pragma unroll
      for (int n=0;n<4;n++){
        int r = wn*64 + n*16 + lr;
        int q = kk*4 + lq;
        bfr[n] = __builtin_bit_cast(bf16x8, *(const u16x8*)&lsB[r*64 + ((q ^ (r&7))<<3)]);
      }
      #pragma unroll
      for (int m=0;m<4;m++)
        #pragma unroll
        for (int n=0;n<4;n++)
          acc[m][n] = __builtin_amdgcn_mfma_f32_16x16x32_bf16(afr[m], bfr[n], acc[m][n], 0, 0, 0);
    }
  }
  #pragma unroll
  for (int m=0;m<4;m++){
    long gr0 = (long)blockIdx.x*128 + wm*64 + m*16 + lq*4;
    #pragma unroll
    for (int n=0;n<4;n++){
      int gc = blockIdx.y*128 + wn*64 + n*16 + lr;
      float bb = biasCol[gz*sBias + gc];
      float tv = (svec!=nullptr) ? tvec[gz*sBias + gc] : 0.0f;
      #pragma unroll
      for (int i=0;i<4;i++){
        long gr = gr0 + i;
        if (gr < M){
          float v = acc[m][n][i] + bb;
          if (svec!=nullptr) v += svec[gz*sS + gr]*tv;
          if (relu) v = fmaxf(v, 0.0f);
          if (EX==0){
            if (Cf) Cf[gz*sCf + gr*(long)N + gc] = v;
            if (Cb){
              float sc = scaleRow ? scaleRow[gz*sSc + gr] : 1.0f;
              Cb[gz*sCb + gr*(long)N + gc] = f2b(v*sc);
            }
          } else if (EX==1){
            Cf[gz*sCf + gr*(long)N + gc] = v;
            float z = -(v + Add[gr*(long)N + gc]) * scaleRow[gr];
            Cb[gz*sCb + gr*(long)N + gc] = f2b(z);
          } else {
            Cf[gz*sCf + gr*(long)N + gc] = v;
            Cf2[gr*(long)N + gc] = v + Add[gr*(long)N + gc];
          }
        }
      }
    }
  }
}

// --------------- GCN aggregation: wave per node, z pre-scaled by dinv ----------
// y_c = dinv_c*(sum_in z_r + z_c); out = bf16(y * (scOut? dinv_c : 1))
__global__ __launch_bounds__(256) void agg_k(
    const u16* __restrict__ xw, long sXW,
    const u16* __restrict__ csr, long sCsr,
    const int* __restrict__ cptr, long sCp,
    const float* __restrict__ dinv, long sD,
    u16* __restrict__ outB, long sOB,
    int totWaves, int scOut)
{
  int wid = (int)((blockIdx.x*256 + threadIdx.x) >> 6);
  if (wid >= totWaves) return;
  int lane = threadIdx.x & 63;
  int g = wid / NV;
  int c = wid - g*NV;
  const u32* xp = (const u32*)(xw + (long)g*sXW);
  const u16* cg = csr + (long)g*sCsr;
  const int* cp = cptr + (long)g*sCp;
  float dc = dinv[(long)g*sD + c];
  u32 u = xp[(long)c*64 + lane];
  float sx = b2f((u16)u), sy = b2f((u16)(u>>16));
  int j0 = cp[c], j1 = cp[c+1];
  int deg = j1 - j0;
  int idx = 0;
  if (lane < deg) idx = cg[j0 + lane];
  int kmax = min(deg, 64);
  int k = 0;
  for (; k+4<=kmax; k+=4){
    int r0=__shfl(idx,k,64), r1=__shfl(idx,k+1,64), r2=__shfl(idx,k+2,64), r3=__shfl(idx,k+3,64);
    u32 v0=xp[(long)r0*64+lane], v1=xp[(long)r1*64+lane];
    u32 v2=xp[(long)r2*64+lane], v3=xp[(long)r3*64+lane];
    sx += b2f((u16)v0); sy += b2f((u16)(v0>>16));
    sx += b2f((u16)v1); sy += b2f((u16)(v1>>16));
    sx += b2f((u16)v2); sy += b2f((u16)(v2>>16));
    sx += b2f((u16)v3); sy += b2f((u16)(v3>>16));
  }
  for (; k<kmax; ++k){
    int r=__shfl(idx,k,64);
    u32 v=xp[(long)r*64+lane];
    sx += b2f((u16)v); sy += b2f((u16)(v>>16));
  }
  for (int j=j0+64; j<j1; ++j){
    int r=cg[j];
    u32 v=xp[(long)r*64+lane];
    sx += b2f((u16)v); sy += b2f((u16)(v>>16));
  }
  float m = scOut ? dc*dc : dc;
  float ox = m*sx, oy = m*sy;
  ((u32*)(outB + (long)g*sOB))[(long)c*64 + lane] = (u32)f2b(ox) | ((u32)f2b(oy)<<16);
}

// --------------- z0 = dinv0 .* (-(enc0+enc1)) as bf16 ----------------
__global__ void ewz_k(const float4* __restrict__ e0, const float4* __restrict__ e1,
                      const float* __restrict__ dinv0, u16* __restrict__ outB){
  int i = blockIdx.x*256 + threadIdx.x;
  if (i >= NH/4) return;
  int row = i>>5;
  float d = dinv0[row];
  float4 a = e0[i], b = e1[i];
  float x0=-d*(a.x+b.x), x1=-d*(a.y+b.y), x2=-d*(a.z+b.z), x3=-d*(a.w+b.w);
  ((uint2*)outB)[i] = make_uint2((u32)f2b(x0) | ((u32)f2b(x1)<<16),
                                 (u32)f2b(x2) | ((u32)f2b(x3)<<16));
}

// --------------- closed-form h2 = s2 (x) t2 + b2 ----------------
__global__ void h2_k(const float* __restrict__ sv2, const float* __restrict__ t2,
                     const float* __restrict__ b2, float4* __restrict__ outF){
  int i = blockIdx.x*256 + threadIdx.x;
  if (i >= NH/4) return;
  int row = i>>5, c4 = i&31;
  float s = sv2[row];
  float4 tv = ((const float4*)t2)[c4];
  float4 bb = ((const float4*)b2)[c4];
  outF[i] = make_float4(s*tv.x+bb.x, s*tv.y+bb.y, s*tv.z+bb.z, s*tv.w+bb.w);
}

__global__ void softmax_k(float* __restrict__ d, int rows){
  int wid = (blockIdx.x*256 + threadIdx.x) >> 6;
  if (wid >= rows) return;
  int lane = threadIdx.x & 63;
  float4* p = (float4*)(d + (long)wid*FD);
  float4 v = p[lane];
  float m = fmaxf(fmaxf(v.x, v.y), fmaxf(v.z, v.w));
  #pragma unroll
  for (int o=32; o; o>>=1) m = fmaxf(m, __shfl_xor(m, o, 64));
  float e0 = __expf(v.x-m), e1 = __expf(v.y-m), e2 = __expf(v.z-m), e3 = __expf(v.w-m);
  float s = e0+e1+e2+e3;
  #pragma unroll
  for (int o=32; o; o>>=1) s += __shfl_xor(s, o, 64);
  float inv = 1.0f/s;
  p[lane] = make_float4(e0*inv, e1*inv, e2*inv, e3*inv);
}

// ===================== host =====================
extern "C" void kernel_launch(void* const* d_in, const int* in_sizes, int n_in,
                              void* d_out, int out_size, void* d_ws, size_t ws_size,
                              hipStream_t stream)
{
  const float* x    = (const float*)d_in[0];
  const int*   ei   = (const int*)  d_in[1];
  const float* fc1W = (const float*)d_in[2];
  const float* fc1b = (const float*)d_in[3];
  const float* c1W  = (const float*)d_in[4];
  const float* c1b  = (const float*)d_in[5];
  const float* c2W  = (const float*)d_in[6];
  const float* c2b  = (const float*)d_in[7];
  const float* d1W  = (const float*)d_in[8];
  const float* d1b  = (const float*)d_in[9];
  const float* d2W  = (const float*)d_in[10];
  const float* d2b  = (const float*)d_in[11];
  const float* fc2W = (const float*)d_in[12];
  const float* fc2b = (const float*)d_in[13];
  (void)in_sizes; (void)n_in; (void)out_size; (void)ws_size;

  float* out  = (float*)d_out;
  float* O_pre = out;
  float* O_enc = out + (long)NG*NH;
  float* O_h   = out + 2L*NG*NH;
  float* O_fin = out + 3L*NG*NH;
  float* O_ls  = O_fin + NH;

  char* p = (char*)d_ws;
  auto alloc = [&](size_t bytes)->void*{
    void* r = (void*)p; p += (bytes + 255) & ~(size_t)255; return r;
  };
  u16* bfA    = (u16*)alloc((size_t)NG*NH*2);
  u16* bfB    = (u16*)alloc((size_t)NG*NH*2);
  u16* bfC    = (u16*)alloc((size_t)NG*NH*2);
  u16* wt_fc1 = (u16*)alloc((size_t)NG*FD*HD*2);
  u16* wt_fc2 = (u16*)alloc((size_t)HD*FD*2);
  u16* wt_ce  = (u16*)alloc((size_t)NG*HD*HD*2);
  u16* wt_cd  = (u16*)alloc((size_t)2*HD*HD*2);
  float* t_enc = (float*)alloc((size_t)NG*HD*4);
  float* t_dec = (float*)alloc((size_t)NG*HD*4);
  u32*  temp  = (u32*) alloc((size_t)NG*ED*4);
  u16*  csr   = (u16*) alloc((size_t)NG*ED*2);
  int*  cptr  = (int*) alloc((size_t)NG*(NV+1)*4);
  int*  btot  = (int*) alloc((size_t)NG*NB*4);
  int*  base  = (int*) alloc((size_t)NG*(NB+1)*4);
  int*  gcur  = (int*) alloc((size_t)NG*NB*4);
  float* dinv = (float*)alloc((size_t)NG*NV*4);
  float* svec = (float*)alloc((size_t)NG*NV*4);

  // ---- binning + CSR + dinv + svec ----
  hipMemsetAsync(btot, 0, (size_t)NG*NB*4, stream);
  histB_k<<<dim3(CH,NG), 256, 0, stream>>>(ei, btot);
  scanB_k<<<1, 1024, 0, stream>>>(btot, base, gcur);
  scat_k<<<dim3(CH,NG), 256, 0, stream>>>(ei, gcur, temp);
  sort_k<<<dim3(NB,NG), 256, 0, stream>>>(temp, base, csr, cptr, dinv);
  svec_k<<<NG*NV/4, 256, 0, stream>>>(csr, cptr, dinv, svec, NG*NV);

  // ---- weight prep: transposes, fused Wc = W1*W2, t vectors ----
  trall_k<<<833, 256, 0, stream>>>(fc1W, fc2W, c1W, c2W, c1b, d1W, d2W, d1b,
                                   wt_fc1, wt_fc2, wt_ce, wt_cd, t_enc, t_dec);

  dim3 g3((NV+127)/128, 1, NG);
  dim3 g1((NV+127)/128, 1, 1);
  dim3 gf((NV+127)/128, 2, 1);

  // ---- encoder (batched over 3 graphs): pre = xW+b; enc = relu(A^2 pre Wc + s*t + b) ----
  gemm_k<1,0><<<g3, 256, 0, stream>>>(x, (long)NV*FD, wt_fc1, (long)FD*HD, fc1b, HD,
                                      nullptr, 0, nullptr, dinv, NV, nullptr,
                                      O_pre, NH, nullptr, bfA, NH, NV, HD, FD, 0);
  agg_k<<<NG*NV/4, 256, 0, stream>>>(bfA, NH, csr, ED, cptr, NV+1, dinv, NV, bfB, NH, NG*NV, 1);
  agg_k<<<NG*NV/4, 256, 0, stream>>>(bfB, NH, csr, ED, cptr, NV+1, dinv, NV, bfC, NH, NG*NV, 0);
  gemm_k<0,0><<<g3, 256, 0, stream>>>(bfC, NH, wt_ce, (long)HD*HD, c2b, HD,
                                      svec, NV, t_enc, nullptr, 0, nullptr,
                                      O_enc, NH, nullptr, nullptr, 0, NV, HD, HD, 1);

  // ---- h2 closed form ----
  h2_k<<<NH/4/256, 256, 0, stream>>>(svec + 2L*NV, t_dec + 2*HD, d2b + 2*HD, (float4*)(O_h + 2L*NH));

  // ---- decoder graph 0: z0 -> A^2 z0 -> h0 (epilogue also emits z1) ----
  ewz_k<<<NH/4/256, 256, 0, stream>>>((const float4*)O_enc, (const float4*)(O_enc+NH), dinv, bfA);
  agg_k<<<NV/4, 256, 0, stream>>>(bfA, 0, csr, 0, cptr, 0, dinv, 0, bfB, 0, NV, 1);
  agg_k<<<NV/4, 256, 0, stream>>>(bfB, 0, csr, 0, cptr, 0, dinv, 0, bfC, 0, NV, 0);
  gemm_k<0,1><<<g1, 256, 0, stream>>>(bfC, 0, wt_cd, 0, d2b, 0,
                                      svec, 0, t_dec, dinv + NV, 0, O_enc + NH,
                                      O_h, 0, nullptr, bfA, 0, NV, HD, HD, 0);

  // ---- decoder graph 1: z1 -> A^2 z1 -> h1 (epilogue also emits fin = h0+h1) ----
  agg_k<<<NV/4, 256, 0, stream>>>(bfA, 0, csr + (long)ED, 0, cptr + (NV+1), 0, dinv + NV, 0, bfB, 0, NV, 1);
  agg_k<<<NV/4, 256, 0, stream>>>(bfB, 0, csr + (long)ED, 0, cptr + (NV+1), 0, dinv + NV, 0, bfC, 0, NV, 0);
  gemm_k<0,2><<<g1, 256, 0, stream>>>(bfC, 0, wt_cd + (long)HD*HD, 0, d2b + HD, 0,
                                      svec + NV, 0, t_dec + HD, nullptr, 0, O_h,
                                      O_h + NH, 0, O_fin, nullptr, 0, NV, HD, HD, 0);

  // ---- fc2 + softmax ----
  gemm_k<1,0><<<gf, 256, 0, stream>>>(O_fin, 0, wt_fc2, 0, fc2b, 0,
                                      nullptr, 0, nullptr, nullptr, 0, nullptr,
                                      O_ls, 0, nullptr, nullptr, 0, NV, FD, HD, 0);
  softmax_k<<<NV/4, 256, 0, stream>>>(O_ls, NV);
}

// Round 6
// 592.377 us; speedup vs baseline: 8.7255x; 1.0192x over previous
//
#include <hip/hip_runtime.h>
#include <hip/hip_bf16.h>

#define NV 40000
#define FD 256
#define HD 128
#define ED 640000
#define NG 3
#define NH (NV*HD)

#define CH  64            // edge chunks per graph
#define EPC (ED/CH)       // 10000 edges per chunk
#define NB  625           // buckets of 64 nodes

typedef unsigned short u16;
typedef unsigned int   u32;
typedef __attribute__((ext_vector_type(8))) u16    u16x8;
typedef __attribute__((ext_vector_type(8))) __bf16 bf16x8;
typedef __attribute__((ext_vector_type(4))) float  f32x4;

__device__ inline u16 f2b(float f){ __bf16 h = (__bf16)f; return __builtin_bit_cast(u16, h); }
__device__ inline float b2f(u16 u){ u32 x = ((u32)u)<<16; return __builtin_bit_cast(float, x); }

// ---------------- binning: bucket hist -> tiny scan -> scatter -> bucket sort ----
__global__ __launch_bounds__(256) void histB_k(const int* __restrict__ ei, int* __restrict__ btot){
  int ch=blockIdx.x, g=blockIdx.y, t=threadIdx.x;
  __shared__ int h[NB];
  for (int i=t;i<NB;i+=256) h[i]=0;
  __syncthreads();
  const int* cc = ei + (long)g*2*ED + ED + ch*EPC;
  for (int j=t;j<EPC;j+=256) atomicAdd(&h[cc[j]>>6],1);
  __syncthreads();
  for (int b=t;b<NB;b+=256){ int v=h[b]; if(v) atomicAdd(&btot[g*NB+b], v); }
}

__global__ void scanB_k(const int* __restrict__ btot, int* __restrict__ base, int* __restrict__ gcur){
  __shared__ int wsum[16];
  int tid=threadIdx.x, lane=tid&63, wv=tid>>6;
  for (int g=0; g<NG; ++g){
    int v = (tid<NB)? btot[g*NB+tid] : 0;
    int s=v;
    #pragma unroll
    for (int d=1; d<64; d<<=1){ int u=__shfl_up(s,d,64); if(lane>=d) s+=u; }
    if (lane==63) wsum[wv]=s;
    __syncthreads();
    if (wv==0){
      int t3=(lane<16)?wsum[lane]:0;
      #pragma unroll
      for (int d=1; d<16; d<<=1){ int u=__shfl_up(t3,d,64); if(lane>=d) t3+=u; }
      if (lane<16) wsum[lane]=t3;
    }
    __syncthreads();
    int incl = s + (wv>0? wsum[wv-1]:0);
    if (tid<NB){
      base[g*(NB+1)+tid]=incl-v;
      gcur[g*NB+tid]=incl-v;
      if (tid==NB-1) base[g*(NB+1)+NB]=incl;
    }
    __syncthreads();
  }
}

__global__ __launch_bounds__(256) void scat_k(const int* __restrict__ ei, int* __restrict__ gcur,
                                              u32* __restrict__ temp){
  int ch=blockIdx.x, g=blockIdx.y, t=threadIdx.x;
  __shared__ int h[NB];
  __shared__ int cur[NB];
  for (int i=t;i<NB;i+=256) h[i]=0;
  __syncthreads();
  const int* rr = ei + (long)g*2*ED + ch*EPC;
  const int* cc = rr + ED;
  for (int j=t;j<EPC;j+=256) atomicAdd(&h[cc[j]>>6],1);
  __syncthreads();
  for (int b=t;b<NB;b+=256){ int v=h[b]; cur[b] = v? atomicAdd(&gcur[g*NB+b], v) : 0; }
  __syncthreads();
  u32* tg = temp + (long)g*ED;
  for (int j=t;j<EPC;j+=256){
    int r=rr[j], c=cc[j];
    int pos=atomicAdd(&cur[c>>6],1);
    tg[pos]=((u32)(c&63)<<16)|(u32)r;
  }
}

// bucket-local counting sort -> u16 CSR + cptr + dinv
__global__ __launch_bounds__(256) void sort_k(const u32* __restrict__ temp, const int* __restrict__ base,
                                              u16* __restrict__ csr, int* __restrict__ cptr,
                                              float* __restrict__ dinv){
  int b=blockIdx.x, g=blockIdx.y, t=threadIdx.x;
  __shared__ int cnt[64];
  __shared__ int cur[64];
  if (t<64) cnt[t]=0;
  __syncthreads();
  const u32* tg = temp + (long)g*ED;
  int s=base[g*(NB+1)+b], e=base[g*(NB+1)+b+1];
  for (int i=s+t;i<e;i+=256) atomicAdd(&cnt[tg[i]>>16],1);
  __syncthreads();
  if (t<64){
    int v=cnt[t];
    int sc=v;
    #pragma unroll
    for (int d=1;d<64;d<<=1){ int u=__shfl_up(sc,d,64); if(t>=d) sc+=u; }
    int st = s + sc - v;
    cur[t]=st;
    cptr[(long)g*(NV+1) + b*64 + t] = st;
    if (b==NB-1 && t==63) cptr[(long)g*(NV+1)+NV] = e;
    dinv[(long)g*NV + b*64 + t] = rsqrtf((float)v+1.0f);
  }
  __syncthreads();
  u16* cg = csr + (long)g*ED;
  for (int i=s+t;i<e;i+=256){
    u32 tt=tg[i];
    int pos=atomicAdd(&cur[tt>>16],1);
    cg[pos]=(u16)(tt&0xFFFF);
  }
}

// --------------- s = A_hat * 1  (per node) ----------------
__global__ __launch_bounds__(256) void svec_k(const u16* __restrict__ csr, const int* __restrict__ cptr,
                                              const float* __restrict__ dinv, float* __restrict__ sv,
                                              int totWaves){
  int wid=(int)((blockIdx.x*256+threadIdx.x)>>6);
  if (wid>=totWaves) return;
  int lane=threadIdx.x&63;
  int g=wid/NV, c=wid-g*NV;
  const u16* cg=csr+(long)g*ED;
  const int* cp=cptr+(long)g*(NV+1);
  const float* dv=dinv+(long)g*NV;
  int j0=cp[c], j1=cp[c+1];
  float sum=0.f;
  for (int j=j0+lane;j<j1;j+=64) sum+=dv[cg[j]];
  #pragma unroll
  for (int o=32;o;o>>=1) sum+=__shfl_xor(sum,o,64);
  if (lane==0){ float dc=dv[c]; sv[(long)g*NV+c]=dc*(dc+sum); }
}

// ---------------- transposes + fused W1*W2 products + t vectors ----------------
__device__ inline void tr_seg(const float* __restrict__ src, u16* __restrict__ dst,
                              int K, int NN, long idx, long total){
  if (idx>=total) return;
  long per=(long)K*NN; long mat=idx/per; long rem=idx-mat*per;
  int k=(int)(rem/NN), c=(int)(rem-(long)k*NN);
  dst[mat*per+(long)c*K+k]=f2b(src[idx]);
}

__global__ __launch_bounds__(256) void trall_k(
    const float* fc1W, const float* fc2W,
    const float* c1W, const float* c2W, const float* c1b,
    const float* d1W, const float* d2W, const float* d1b,
    u16* w_fc1, u16* w_fc2, u16* w_ce, u16* w_cd,
    float* t_enc, float* t_dec)
{
  int blk=blockIdx.x, t=threadIdx.x;
  if (blk < 384){            // fc1 transpose, 3 graphs
    tr_seg(fc1W, w_fc1, FD, HD, (long)blk*256+t, (long)NG*FD*HD);
  } else if (blk < 512){     // fc2 transpose
    tr_seg(fc2W, w_fc2, HD, FD, (long)(blk-384)*256+t, (long)HD*FD);
  } else if (blk < 832){     // 5 fused products Wc = W1*W2, output [N][K] bf16
    int bb=blk-512;
    int mat=bb>>6;
    int local=(bb&63)*256+t;
    int n=local>>7, k=local&127;
    const float* W1; const float* W2; u16* dst;
    if (mat<3){ W1=c1W+(long)mat*HD*HD; W2=c2W+(long)mat*HD*HD; dst=w_ce+(long)mat*HD*HD; }
    else { int md=mat-3; W1=d1W+(long)md*HD*HD; W2=d2W+(long)md*HD*HD; dst=w_cd+(long)md*HD*HD; }
    float s=0.f;
    for (int j=0;j<HD;j++) s += W1[k*HD+j]*W2[j*HD+n];
    dst[(long)n*HD+k]=f2b(s);
  } else {                   // t vectors: t = b1 @ W2  (6 of them, 768 elements total)
    for (int idx=t; idx<768; idx+=256){
      int which=idx>>7, n=idx&127;
      const float* b; const float* W; float* dst;
      if (which<3){ b=c1b+which*HD; W=c2W+(long)which*HD*HD; dst=t_enc+which*HD; }
      else { int w2=which-3; b=d1b+w2*HD; W=d2W+(long)w2*HD*HD; dst=t_dec+w2*HD; }
      float s=0.f;
      for (int k=0;k<HD;k++) s += b[k]*W[(long)k*HD+n];
      dst[n]=s;
    }
  }
}

// --------------- bf16 MFMA GEMM, 128x128 tile, BK=64 -----------------
// MODE: 0 = A bf16, 1 = A f32.
// EX: 0 plain (Cf opt, Cb=f2b(v*scale) opt)
//     1 dec0  (Cf=v; Cb=f2b(scale[row]*(-(v+Add[row][col]))))
//     2 dec1  (Cf=v; Cf2=v+Add[row][col]; Cb=f2b(Cf2))
// epilogue v = acc + biasCol + (svec? svec[row]*tvec[col] : 0); optional relu.
template<int MODE, int EX>
__global__ __launch_bounds__(256) void gemm_k(
    const void* __restrict__ A_, long sA,
    const u16* __restrict__ Bt, long sB,
    const float* __restrict__ biasCol, long sBias,
    const float* __restrict__ svec, long sS,
    const float* __restrict__ tvec,
    const float* __restrict__ scaleRow, long sSc,
    const float* __restrict__ Add,
    float* __restrict__ Cf, long sCf,
    float* __restrict__ Cf2,
    u16* __restrict__ Cb, long sCb,
    int M, int N, int K, int relu)
{
  __shared__ __align__(16) u16 lsA[128*64];
  __shared__ __align__(16) u16 lsB[128*64];
  const int gz = blockIdx.z;
  const float* Af = (const float*)A_ + (long)gz*sA;
  const u16*   Ab = (const u16*)  A_ + (long)gz*sA;
  const u16* Bp = Bt + (long)gz*sB;
  const int t = threadIdx.x;
  const int lane = t & 63, wv = t >> 6, wm = wv >> 1, wn = wv & 1;
  const int lr = lane & 15, lq = lane >> 4;
  const int ar = t >> 1, ah = t & 1;
  const long grow = (long)blockIdx.x*128 + ar;
  const int colB = blockIdx.y*128 + ar;

  f32x4 acc[4][4];
  #pragma unroll
  for (int m=0;m<4;m++)
    #pragma unroll
    for (int n=0;n<4;n++) acc[m][n] = (f32x4)(0.0f);

  for (int k0=0; k0<K; k0+=64){
    if (k0) __syncthreads();
    u16x8 av[4];
    if (grow < M){
      if (MODE==0){
        const u16x8* s = (const u16x8*)(Ab + grow*(long)K + k0 + ah*32);
        #pragma unroll
        for (int i=0;i<4;i++) av[i] = s[i];
      } else {
        const float4* s = (const float4*)(Af + grow*(long)K + k0 + ah*32);
        #pragma unroll
        for (int i=0;i<4;i++){
          float4 v0 = s[i*2], v1 = s[i*2+1];
          u16x8 w;
          w[0]=f2b(v0.x); w[1]=f2b(v0.y); w[2]=f2b(v0.z); w[3]=f2b(v0.w);
          w[4]=f2b(v1.x); w[5]=f2b(v1.y); w[6]=f2b(v1.z); w[7]=f2b(v1.w);
          av[i] = w;
        }
      }
    } else {
      #pragma unroll
      for (int i=0;i<4;i++) av[i] = (u16x8)((u16)0);
    }
    #pragma unroll
    for (int i=0;i<4;i++){
      int q = ah*4 + i;
      *(u16x8*)&lsA[ar*64 + ((q ^ (ar&7))<<3)] = av[i];
    }
    {
      const u16x8* s = (const u16x8*)(Bp + (long)colB*K + k0 + ah*32);
      #pragma unroll
      for (int i=0;i<4;i++){
        int q = ah*4 + i;
        *(u16x8*)&lsB[ar*64 + ((q ^ (ar&7))<<3)] = s[i];
      }
    }
    __syncthreads();
    #pragma unroll
    for (int kk=0; kk<2; kk++){
      bf16x8 afr[4], bfr[4];
      #pragma unroll
      for (int m=0;m<4;m++){
        int r = wm*64 + m*16 + lr;
        int q = kk*4 + lq;
        afr[m] = __builtin_bit_cast(bf16x8, *(const u16x8*)&lsA[r*64 + ((q ^ (r&7))<<3)]);
      }
      #pragma unroll
      for (int n=0;n<4;n++){
        int r = wn*64 + n*16 + lr;
        int q = kk*4 + lq;
        bfr[n] = __builtin_bit_cast(bf16x8, *(const u16x8*)&lsB[r*64 + ((q ^ (r&7))<<3)]);
      }
      #pragma unroll
      for (int m=0;m<4;m++)
        #pragma unroll
        for (int n=0;n<4;n++)
          acc[m][n] = __builtin_amdgcn_mfma_f32_16x16x32_bf16(afr[m], bfr[n], acc[m][n], 0, 0, 0);
    }
  }
  #pragma unroll
  for (int m=0;m<4;m++){
    long gr0 = (long)blockIdx.x*128 + wm*64 + m*16 + lq*4;
    #pragma unroll
    for (int n=0;n<4;n++){
      int gc = blockIdx.y*128 + wn*64 + n*16 + lr;
      float bb = biasCol[gz*sBias + gc];
      float tv = (svec!=nullptr) ? tvec[gz*sBias + gc] : 0.0f;
      #pragma unroll
      for (int i=0;i<4;i++){
        long gr = gr0 + i;
        if (gr < M){
          float v = acc[m][n][i] + bb;
          if (svec!=nullptr) v += svec[gz*sS + gr]*tv;
          if (relu) v = fmaxf(v, 0.0f);
          if (EX==0){
            if (Cf) Cf[gz*sCf + gr*(long)N + gc] = v;
            if (Cb){
              float sc = scaleRow ? scaleRow[gz*sSc + gr] : 1.0f;
              Cb[gz*sCb + gr*(long)N + gc] = f2b(v*sc);
            }
          } else if (EX==1){
            Cf[gz*sCf + gr*(long)N + gc] = v;
            float z = -(v + Add[gr*(long)N + gc]) * scaleRow[gr];
            Cb[gz*sCb + gr*(long)N + gc] = f2b(z);
          } else {
            Cf[gz*sCf + gr*(long)N + gc] = v;
            float fv = v + Add[gr*(long)N + gc];
            Cf2[gr*(long)N + gc] = fv;
            if (Cb) Cb[gz*sCb + gr*(long)N + gc] = f2b(fv);
          }
        }
      }
    }
  }
}

// --------------- GCN aggregation: wave per node, z pre-scaled by dinv ----------
// y_c = dinv_c*(sum_in z_r + z_c); out = bf16(y * (scOut? dinv_c : 1))
__global__ __launch_bounds__(256) void agg_k(
    const u16* __restrict__ xw, long sXW,
    const u16* __restrict__ csr, long sCsr,
    const int* __restrict__ cptr, long sCp,
    const float* __restrict__ dinv, long sD,
    u16* __restrict__ outB, long sOB,
    int totWaves, int scOut)
{
  int wid = (int)((blockIdx.x*256 + threadIdx.x) >> 6);
  if (wid >= totWaves) return;
  int lane = threadIdx.x & 63;
  int g = wid / NV;
  int c = wid - g*NV;
  const u32* xp = (const u32*)(xw + (long)g*sXW);
  const u16* cg = csr + (long)g*sCsr;
  const int* cp = cptr + (long)g*sCp;
  float dc = dinv[(long)g*sD + c];
  u32 u = xp[(c<<6) + lane];
  float sx = b2f((u16)u), sy = b2f((u16)(u>>16));
  int j0 = cp[c], j1 = cp[c+1];
  int deg = j1 - j0;
  int idx = 0;
  if (lane < deg) idx = cg[j0 + lane];
  int kmax = min(deg, 64);
  int k = 0;
  for (; k+8<=kmax; k+=8){
    int r0=__shfl(idx,k,64),   r1=__shfl(idx,k+1,64), r2=__shfl(idx,k+2,64), r3=__shfl(idx,k+3,64);
    int r4=__shfl(idx,k+4,64), r5=__shfl(idx,k+5,64), r6=__shfl(idx,k+6,64), r7=__shfl(idx,k+7,64);
    u32 v0=xp[(r0<<6)+lane], v1=xp[(r1<<6)+lane], v2=xp[(r2<<6)+lane], v3=xp[(r3<<6)+lane];
    u32 v4=xp[(r4<<6)+lane], v5=xp[(r5<<6)+lane], v6=xp[(r6<<6)+lane], v7=xp[(r7<<6)+lane];
    sx += b2f((u16)v0); sy += b2f((u16)(v0>>16));
    sx += b2f((u16)v1); sy += b2f((u16)(v1>>16));
    sx += b2f((u16)v2); sy += b2f((u16)(v2>>16));
    sx += b2f((u16)v3); sy += b2f((u16)(v3>>16));
    sx += b2f((u16)v4); sy += b2f((u16)(v4>>16));
    sx += b2f((u16)v5); sy += b2f((u16)(v5>>16));
    sx += b2f((u16)v6); sy += b2f((u16)(v6>>16));
    sx += b2f((u16)v7); sy += b2f((u16)(v7>>16));
  }
  for (; k+4<=kmax; k+=4){
    int r0=__shfl(idx,k,64), r1=__shfl(idx,k+1,64), r2=__shfl(idx,k+2,64), r3=__shfl(idx,k+3,64);
    u32 v0=xp[(r0<<6)+lane], v1=xp[(r1<<6)+lane], v2=xp[(r2<<6)+lane], v3=xp[(r3<<6)+lane];
    sx += b2f((u16)v0); sy += b2f((u16)(v0>>16));
    sx += b2f((u16)v1); sy += b2f((u16)(v1>>16));
    sx += b2f((u16)v2); sy += b2f((u16)(v2>>16));
    sx += b2f((u16)v3); sy += b2f((u16)(v3>>16));
  }
  for (; k<kmax; ++k){
    int r=__shfl(idx,k,64);
    u32 v=xp[(r<<6)+lane];
    sx += b2f((u16)v); sy += b2f((u16)(v>>16));
  }
  for (int j=j0+64; j<j1; ++j){
    int r=cg[j];
    u32 v=xp[(r<<6)+lane];
    sx += b2f((u16)v); sy += b2f((u16)(v>>16));
  }
  float m = scOut ? dc*dc : dc;
  float ox = m*sx, oy = m*sy;
  ((u32*)(outB + (long)g*sOB))[(c<<6) + lane] = (u32)f2b(ox) | ((u32)f2b(oy)<<16);
}

// --------------- merged: z0 = dinv0.*(-(enc0+enc1)) bf16  AND  h2 = s2(x)t2+b2 ----
__global__ void ewzh2_k(const float4* __restrict__ e0, const float4* __restrict__ e1,
                        const float* __restrict__ dinv0, u16* __restrict__ outB,
                        const float* __restrict__ sv2, const float* __restrict__ t2,
                        const float* __restrict__ b2, float4* __restrict__ outH2){
  int blk = blockIdx.x;
  if (blk < (NH/4)/256){
    int i = blk*256 + threadIdx.x;
    int row = i>>5;
    float d = dinv0[row];
    float4 a = e0[i], b = e1[i];
    float x0=-d*(a.x+b.x), x1=-d*(a.y+b.y), x2=-d*(a.z+b.z), x3=-d*(a.w+b.w);
    ((uint2*)outB)[i] = make_uint2((u32)f2b(x0) | ((u32)f2b(x1)<<16),
                                   (u32)f2b(x2) | ((u32)f2b(x3)<<16));
  } else {
    int i = (blk - (NH/4)/256)*256 + threadIdx.x;
    int row = i>>5, c4 = i&31;
    float s = sv2[row];
    float4 tv = ((const float4*)t2)[c4];
    float4 bb = ((const float4*)b2)[c4];
    outH2[i] = make_float4(s*tv.x+bb.x, s*tv.y+bb.y, s*tv.z+bb.z, s*tv.w+bb.w);
  }
}

// --------------- fc2 + row softmax fused: A bf16 [M][128], B [256][128] ----------
__global__ __launch_bounds__(256) void fc2sm_k(
    const u16* __restrict__ Ab, const u16* __restrict__ Bw,
    const float* __restrict__ bias, float* __restrict__ Out, int M)
{
  __shared__ __align__(16) u16 lsA[128*64];
  __shared__ __align__(16) u16 lsB[256*64];
  const int t = threadIdx.x;
  const int lane = t & 63, wv = t >> 6, wm = wv >> 1, wn = wv & 1;
  const int lr = lane & 15, lq = lane >> 4;
  const int ar = t >> 1, ah = t & 1;
  const long grow = (long)blockIdx.x*128 + ar;

  f32x4 acc[4][8];
  #pragma unroll
  for (int m=0;m<4;m++)
    #pragma unroll
    for (int n=0;n<8;n++) acc[m][n] = (f32x4)(0.0f);

  for (int k0=0; k0<128; k0+=64){
    if (k0) __syncthreads();
    // stage A (rows of fin, bf16)
    {
      u16x8 av[4];
      if (grow < M){
        const u16x8* s = (const u16x8*)(Ab + grow*128L + k0 + ah*32);
        #pragma unroll
        for (int i=0;i<4;i++) av[i] = s[i];
      } else {
        #pragma unroll
        for (int i=0;i<4;i++) av[i] = (u16x8)((u16)0);
      }
      #pragma unroll
      for (int i=0;i<4;i++){
        int q = ah*4 + i;
        *(u16x8*)&lsA[ar*64 + ((q ^ (ar&7))<<3)] = av[i];
      }
    }
    // stage B: all 256 rows (output cols), 64 k each
    #pragma unroll
    for (int rr=0; rr<2; rr++){
      int r = ar + rr*128;
      const u16x8* s = (const u16x8*)(Bw + (long)r*128 + k0 + ah*32);
      #pragma unroll
      for (int i=0;i<4;i++){
        int q = ah*4 + i;
        *(u16x8*)&lsB[r*64 + ((q ^ (r&7))<<3)] = s[i];
      }
    }
    __syncthreads();
    #pragma unroll
    for (int kk=0; kk<2; kk++){
      bf16x8 afr[4], bfr[8];
      #pragma unroll
      for (int m=0;m<4;m++){
        int r = wm*64 + m*16 + lr;
        int q = kk*4 + lq;
        afr[m] = __builtin_bit_cast(bf16x8, *(const u16x8*)&lsA[r*64 + ((q ^ (r&7))<<3)]);
      }
      #pragma unroll
      for (int n=0;n<8;n++){
        int r = wn*128 + n*16 + lr;
        int q = kk*4 + lq;
        bfr[n] = __builtin_bit_cast(bf16x8, *(const u16x8*)&lsB[r*64 + ((q ^ (r&7))<<3)]);
      }
      #pragma unroll
      for (int m=0;m<4;m++)
        #pragma unroll
        for (int n=0;n<8;n++)
          acc[m][n] = __builtin_amdgcn_mfma_f32_16x16x32_bf16(afr[m], bfr[n], acc[m][n], 0, 0, 0);
    }
  }
  // add bias in place
  #pragma unroll
  for (int n=0;n<8;n++){
    float bb = bias[wn*128 + n*16 + lr];
    #pragma unroll
    for (int m=0;m<4;m++)
      #pragma unroll
      for (int i=0;i<4;i++) acc[m][n][i] += bb;
  }
  __syncthreads();           // reuse lsA as float scratch
  float* lsF = (float*)lsA;  // [0..256): row maxes [rl*2+wn]; [256..512): row sums
  // per-row max across this wave's 128 cols
  float pmax[4][4];
  #pragma unroll
  for (int m=0;m<4;m++)
    #pragma unroll
    for (int i=0;i<4;i++){
      float v = acc[m][0][i];
      #pragma unroll
      for (int n=1;n<8;n++) v = fmaxf(v, acc[m][n][i]);
      #pragma unroll
      for (int o=8;o;o>>=1) v = fmaxf(v, __shfl_xor(v, o, 16));
      pmax[m][i] = v;
      if (lr==0) lsF[(wm*64 + m*16 + lq*4 + i)*2 + wn] = v;
    }
  __syncthreads();
  float psum[4][4];
  #pragma unroll
  for (int m=0;m<4;m++)
    #pragma unroll
    for (int i=0;i<4;i++){
      int rl = wm*64 + m*16 + lq*4 + i;
      float rm = fmaxf(lsF[rl*2], lsF[rl*2+1]);
      float s = 0.f;
      #pragma unroll
      for (int n=0;n<8;n++){
        float e = __expf(acc[m][n][i] - rm);
        acc[m][n][i] = e;
        s += e;
      }
      #pragma unroll
      for (int o=8;o;o>>=1) s += __shfl_xor(s, o, 16);
      psum[m][i] = s;
      if (lr==0) lsF[256 + rl*2 + wn] = s;
    }
  __syncthreads();
  #pragma unroll
  for (int m=0;m<4;m++){
    long gr0 = (long)blockIdx.x*128 + wm*64 + m*16 + lq*4;
    #pragma unroll
    for (int i=0;i<4;i++){
      long gr = gr0 + i;
      if (gr < M){
        int rl = wm*64 + m*16 + lq*4 + i;
        float inv = 1.0f/(lsF[256 + rl*2] + lsF[256 + rl*2 + 1]);
        #pragma unroll
        for (int n=0;n<8;n++){
          int gc = wn*128 + n*16 + lr;
          Out[gr*256L + gc] = acc[m][n][i]*inv;
        }
      }
    }
  }
}

// ===================== host =====================
extern "C" void kernel_launch(void* const* d_in, const int* in_sizes, int n_in,
                              void* d_out, int out_size, void* d_ws, size_t ws_size,
                              hipStream_t stream)
{
  const float* x    = (const float*)d_in[0];
  const int*   ei   = (const int*)  d_in[1];
  const float* fc1W = (const float*)d_in[2];
  const float* fc1b = (const float*)d_in[3];
  const float* c1W  = (const float*)d_in[4];
  const float* c1b  = (const float*)d_in[5];
  const float* c2W  = (const float*)d_in[6];
  const float* c2b  = (const float*)d_in[7];
  const float* d1W  = (const float*)d_in[8];
  const float* d1b  = (const float*)d_in[9];
  const float* d2W  = (const float*)d_in[10];
  const float* d2b  = (const float*)d_in[11];
  const float* fc2W = (const float*)d_in[12];
  const float* fc2b = (const float*)d_in[13];
  (void)in_sizes; (void)n_in; (void)out_size; (void)ws_size;

  float* out  = (float*)d_out;
  float* O_pre = out;
  float* O_enc = out + (long)NG*NH;
  float* O_h   = out + 2L*NG*NH;
  float* O_fin = out + 3L*NG*NH;
  float* O_ls  = O_fin + NH;

  char* p = (char*)d_ws;
  auto alloc = [&](size_t bytes)->void*{
    void* r = (void*)p; p += (bytes + 255) & ~(size_t)255; return r;
  };
  u16* bfA    = (u16*)alloc((size_t)NG*NH*2);
  u16* bfB    = (u16*)alloc((size_t)NG*NH*2);
  u16* bfC    = (u16*)alloc((size_t)NG*NH*2);
  u16* wt_fc1 = (u16*)alloc((size_t)NG*FD*HD*2);
  u16* wt_fc2 = (u16*)alloc((size_t)HD*FD*2);
  u16* wt_ce  = (u16*)alloc((size_t)NG*HD*HD*2);
  u16* wt_cd  = (u16*)alloc((size_t)2*HD*HD*2);
  float* t_enc = (float*)alloc((size_t)NG*HD*4);
  float* t_dec = (float*)alloc((size_t)NG*HD*4);
  u32*  temp  = (u32*) alloc((size_t)NG*ED*4);
  u16*  csr   = (u16*) alloc((size_t)NG*ED*2);
  int*  cptr  = (int*) alloc((size_t)NG*(NV+1)*4);
  int*  btot  = (int*) alloc((size_t)NG*NB*4);
  int*  base  = (int*) alloc((size_t)NG*(NB+1)*4);
  int*  gcur  = (int*) alloc((size_t)NG*NB*4);
  float* dinv = (float*)alloc((size_t)NG*NV*4);
  float* svec = (float*)alloc((size_t)NG*NV*4);

  // ---- binning + CSR + dinv + svec ----
  hipMemsetAsync(btot, 0, (size_t)NG*NB*4, stream);
  histB_k<<<dim3(CH,NG), 256, 0, stream>>>(ei, btot);
  scanB_k<<<1, 1024, 0, stream>>>(btot, base, gcur);
  scat_k<<<dim3(CH,NG), 256, 0, stream>>>(ei, gcur, temp);
  sort_k<<<dim3(NB,NG), 256, 0, stream>>>(temp, base, csr, cptr, dinv);
  svec_k<<<NG*NV/4, 256, 0, stream>>>(csr, cptr, dinv, svec, NG*NV);

  // ---- weight prep: transposes, fused Wc = W1*W2, t vectors ----
  trall_k<<<833, 256, 0, stream>>>(fc1W, fc2W, c1W, c2W, c1b, d1W, d2W, d1b,
                                   wt_fc1, wt_fc2, wt_ce, wt_cd, t_enc, t_dec);

  dim3 g3((NV+127)/128, 1, NG);
  dim3 g1((NV+127)/128, 1, 1);

  // ---- encoder (batched over 3 graphs): pre = xW+b; enc = relu(A^2 pre Wc + s*t + b) ----
  gemm_k<1,0><<<g3, 256, 0, stream>>>(x, (long)NV*FD, wt_fc1, (long)FD*HD, fc1b, HD,
                                      nullptr, 0, nullptr, dinv, NV, nullptr,
                                      O_pre, NH, nullptr, bfA, NH, NV, HD, FD, 0);
  agg_k<<<NG*NV/4, 256, 0, stream>>>(bfA, NH, csr, ED, cptr, NV+1, dinv, NV, bfB, NH, NG*NV, 1);
  agg_k<<<NG*NV/4, 256, 0, stream>>>(bfB, NH, csr, ED, cptr, NV+1, dinv, NV, bfC, NH, NG*NV, 0);
  gemm_k<0,0><<<g3, 256, 0, stream>>>(bfC, NH, wt_ce, (long)HD*HD, c2b, HD,
                                      svec, NV, t_enc, nullptr, 0, nullptr,
                                      O_enc, NH, nullptr, nullptr, 0, NV, HD, HD, 1);

  // ---- merged: z0 prep (needs enc) + h2 closed form ----
  ewzh2_k<<<2*(NH/4)/256, 256, 0, stream>>>((const float4*)O_enc, (const float4*)(O_enc+NH), dinv, bfA,
                                            svec + 2L*NV, t_dec + 2*HD, d2b + 2*HD,
                                            (float4*)(O_h + 2L*NH));

  // ---- decoder graph 0: z0 -> A^2 z0 -> h0 (epilogue also emits z1) ----
  agg_k<<<NV/4, 256, 0, stream>>>(bfA, 0, csr, 0, cptr, 0, dinv, 0, bfB, 0, NV, 1);
  agg_k<<<NV/4, 256, 0, stream>>>(bfB, 0, csr, 0, cptr, 0, dinv, 0, bfC, 0, NV, 0);
  gemm_k<0,1><<<g1, 256, 0, stream>>>(bfC, 0, wt_cd, 0, d2b, 0,
                                      svec, 0, t_dec, dinv + NV, 0, O_enc + NH,
                                      O_h, 0, nullptr, bfA, 0, NV, HD, HD, 0);

  // ---- decoder graph 1: z1 -> A^2 z1 -> h1 (epilogue emits fin f32 + fin bf16) ----
  agg_k<<<NV/4, 256, 0, stream>>>(bfA, 0, csr + (long)ED, 0, cptr + (NV+1), 0, dinv + NV, 0, bfB, 0, NV, 1);
  agg_k<<<NV/4, 256, 0, stream>>>(bfB, 0, csr + (long)ED, 0, cptr + (NV+1), 0, dinv + NV, 0, bfC, 0, NV, 0);
  gemm_k<0,2><<<g1, 256, 0, stream>>>(bfC, 0, wt_cd + (long)HD*HD, 0, d2b + HD, 0,
                                      svec + NV, 0, t_dec + HD, nullptr, 0, O_h,
                                      O_h + NH, 0, O_fin, bfA, 0, NV, HD, HD, 0);

  // ---- fc2 + softmax (fused) ----
  fc2sm_k<<<(NV+127)/128, 256, 0, stream>>>(bfA, wt_fc2, fc2b, O_ls, NV);
}